// Round 6
// baseline (1331.386 us; speedup 1.0000x reference)
//
#include <hip/hip_runtime.h>
#include <hip/hip_bf16.h>

// AKT forward, round 6: swapped-QK MFMA flash attention (lane-local softmax,
// zero-exchange PV via key-permuted fragments, no LDS in attn).
//   - glo term dropped (softmax-invariant per-query constant)
//   - pos_key folded into k-GEMM epilogue
// Workspace (64 MB): Xc[4096,2048]bf16 (aliased by Vt after embed) |
//   X,Q,K,V [4096,1024]bf16 | W_in bf16 | Wbuf 6x1M bf16

#define B_ 4
#define S_ 1024
#define E_ 1024
#define H_ 16
#define D_ 64
#define L_ 4
#define M_ (B_ * S_)  // 4096
#define EE (E_ * E_)  // 1M

typedef __attribute__((ext_vector_type(8))) __bf16 bf16x8;
typedef __attribute__((ext_vector_type(4))) __bf16 bf16x4;
typedef __attribute__((ext_vector_type(4))) float f32x4;
typedef __attribute__((ext_vector_type(8))) unsigned short u16x8;

__device__ __forceinline__ float bf2f(unsigned short u) {
    union { unsigned int i; float f; } x;
    x.i = ((unsigned int)u) << 16;
    return x.f;
}
__device__ __forceinline__ float gelu_exact(float x) {
    return 0.5f * x * (1.0f + erff(x * 0.70710678118654752f));
}

// ---------------------------------------------------------------------------
// f32 -> bf16 bulk convert
// ---------------------------------------------------------------------------
__global__ __launch_bounds__(256) void cvt_f32_bf16(
    const float* __restrict__ in, __bf16* __restrict__ out, int n) {
    const int i = (blockIdx.x * 256 + threadIdx.x) * 4;
    if (i >= n) return;
    const float4 v = *(const float4*)(in + i);
    __bf16* o = out + i;
    o[0] = (__bf16)v.x; o[1] = (__bf16)v.y; o[2] = (__bf16)v.z; o[3] = (__bf16)v.w;
}

// per-layer: Wq,Wk,Wv,Wl[0..2] (each 1M f32) -> Wbuf[6M] bf16
__global__ __launch_bounds__(256) void cvt_layer_weights(
    const float* __restrict__ Wq, const float* __restrict__ Wk,
    const float* __restrict__ Wv, const float* __restrict__ Wl,
    __bf16* __restrict__ out) {
    const int i = (blockIdx.x * 256 + threadIdx.x) * 4;  // < 6M
    const int mat = i >> 20;
    const int off = i & (EE - 1);
    const float* src = (mat == 0) ? Wq : (mat == 1) ? Wk : (mat == 2) ? Wv
                                        : Wl + (size_t)(mat - 3) * EE;
    const float4 v = *(const float4*)(src + off);
    __bf16* o = out + i;
    o[0] = (__bf16)v.x; o[1] = (__bf16)v.y; o[2] = (__bf16)v.z; o[3] = (__bf16)v.w;
}

// ---------------------------------------------------------------------------
// Xc[r, 0:2048] = bf16(concat(emb_item[item_idx[r]], emb_skill[skill_idx[r]]))
// ---------------------------------------------------------------------------
__global__ __launch_bounds__(256) void embed_gather(
    const int* __restrict__ item_idx, const int* __restrict__ skill_idx,
    const float* __restrict__ emb_item, const float* __restrict__ emb_skill,
    __bf16* __restrict__ Xc) {
    const int r = blockIdx.x;
    const int c = threadIdx.x * 8;
    const float* s = (c < E_) ? emb_item + (size_t)item_idx[r] * E_ + c
                              : emb_skill + (size_t)skill_idx[r] * E_ + (c - E_);
    const float4 a = *(const float4*)s;
    const float4 b = *(const float4*)(s + 4);
    __bf16* o = Xc + (size_t)r * 2048 + c;
    o[0] = (__bf16)a.x; o[1] = (__bf16)a.y; o[2] = (__bf16)a.z; o[3] = (__bf16)a.w;
    o[4] = (__bf16)b.x; o[5] = (__bf16)b.y; o[6] = (__bf16)b.z; o[7] = (__bf16)b.w;
}

// ---------------------------------------------------------------------------
// C[M_,1024]bf16 = A[M_,K]bf16 * Bm[1024,K]bf16^T + bias(f32); opt GELU / pe.
// BM=128, BN=64, BK=32. 256 threads = 4 waves (2x2), wave tile 64x32.
// ---------------------------------------------------------------------------
template <int ACT, int ADD_PE>
__global__ __launch_bounds__(256) void gemm_bf16(
    const __bf16* __restrict__ A, const __bf16* __restrict__ Bm,
    const float* __restrict__ bias, __bf16* __restrict__ C, int K,
    const float* __restrict__ pe) {
    __shared__ __bf16 As[128 * 32];
    __shared__ __bf16 Bs[64 * 32];
    const int tid = threadIdx.x;
    const int lane = tid & 63;
    const int wid = tid >> 6;
    const int wm = wid >> 1;
    const int wn = wid & 1;
    const int m0 = blockIdx.y * 128;
    const int n0 = blockIdx.x * 64;

    const int ca0 = wid * 128 + lane;
    const int ca1 = ca0 + 64;
    const int cb = wid * 64 + lane;
    const int ra0 = ca0 >> 2, ga0 = (ca0 & 3) ^ (ra0 & 3);
    const int ra1 = ca1 >> 2, ga1 = (ca1 & 3) ^ (ra1 & 3);
    const int rb = cb >> 2, gb = (cb & 3) ^ (rb & 3);
    const __bf16* pa0 = A + (size_t)(m0 + ra0) * K + ga0 * 8;
    const __bf16* pa1 = A + (size_t)(m0 + ra1) * K + ga1 * 8;
    const __bf16* pb = Bm + (size_t)(n0 + rb) * K + gb * 8;
    __bf16* lda0 = As + (size_t)(wid * 128) * 8;
    __bf16* lda1 = As + (size_t)(wid * 128 + 64) * 8;
    __bf16* ldb = Bs + (size_t)(wid * 64) * 8;

    const int acg = lane >> 4;
    int aoff[4], boff[2];
#pragma unroll
    for (int mi = 0; mi < 4; ++mi) {
        const int row = wm * 64 + mi * 16 + (lane & 15);
        aoff[mi] = row * 32 + ((acg ^ (row & 3)) << 3);
    }
#pragma unroll
    for (int ni = 0; ni < 2; ++ni) {
        const int row = wn * 32 + ni * 16 + (lane & 15);
        boff[ni] = row * 32 + ((acg ^ (row & 3)) << 3);
    }

    f32x4 acc[4][2] = {};

    for (int k0 = 0; k0 < K; k0 += 32) {
        __builtin_amdgcn_global_load_lds(
            (const __attribute__((address_space(1))) unsigned int*)(pa0 + k0),
            (__attribute__((address_space(3))) unsigned int*)lda0, 16, 0, 0);
        __builtin_amdgcn_global_load_lds(
            (const __attribute__((address_space(1))) unsigned int*)(pa1 + k0),
            (__attribute__((address_space(3))) unsigned int*)lda1, 16, 0, 0);
        __builtin_amdgcn_global_load_lds(
            (const __attribute__((address_space(1))) unsigned int*)(pb + k0),
            (__attribute__((address_space(3))) unsigned int*)ldb, 16, 0, 0);
        __syncthreads();
        bf16x8 af[4], bfr[2];
#pragma unroll
        for (int mi = 0; mi < 4; ++mi) af[mi] = *(const bf16x8*)(As + aoff[mi]);
#pragma unroll
        for (int ni = 0; ni < 2; ++ni) bfr[ni] = *(const bf16x8*)(Bs + boff[ni]);
#pragma unroll
        for (int mi = 0; mi < 4; ++mi)
#pragma unroll
            for (int ni = 0; ni < 2; ++ni)
                acc[mi][ni] = __builtin_amdgcn_mfma_f32_16x16x32_bf16(
                    af[mi], bfr[ni], acc[mi][ni], 0, 0, 0);
        __syncthreads();
    }

    const int ccol0 = n0 + wn * 32 + (lane & 15);
    const int crow0 = m0 + wm * 64 + ((lane >> 4) << 2);
#pragma unroll
    for (int mi = 0; mi < 4; ++mi) {
#pragma unroll
        for (int ni = 0; ni < 2; ++ni) {
            const int col = ccol0 + ni * 16;
            const float bsum = bias[col];
#pragma unroll
            for (int r = 0; r < 4; ++r) {
                const int row = crow0 + mi * 16 + r;
                float v = acc[mi][ni][r] + bsum;
                if (ADD_PE) v += pe[((row & (S_ - 1)) << 6) + (col & (D_ - 1))];
                if (ACT) v = gelu_exact(v);
                C[(size_t)row * E_ + col] = (__bf16)v;
            }
        }
    }
}

// ---------------------------------------------------------------------------
// Vt[(bh*64 + d)*1024 + s] = Vb[(b*1024+s)*1024 + h*64 + d]
// ---------------------------------------------------------------------------
__global__ __launch_bounds__(256) void v_transpose(
    const __bf16* __restrict__ Vb, __bf16* __restrict__ Vt) {
    __shared__ unsigned short T[64][72];
    const int tid = threadIdx.x;
    const int s0 = blockIdx.x * 64;
    const int bh = blockIdx.y;
    const int b = bh >> 4, h = bh & 15;
    const unsigned short* Vu = (const unsigned short*)Vb;
#pragma unroll
    for (int p = 0; p < 2; ++p) {
        const int sl = p * 32 + (tid >> 3);
        const int dc = (tid & 7) * 8;
        const u16x8 v = *(const u16x8*)(Vu + (size_t)(b * S_ + s0 + sl) * E_ + h * 64 + dc);
#pragma unroll
        for (int j = 0; j < 8; ++j) T[dc + j][sl] = v[j];
    }
    __syncthreads();
    const int d = tid >> 2;
    const int c = (tid & 3) * 16;
    const u16x8 a = *(const u16x8*)&T[d][c];
    const u16x8 bvv = *(const u16x8*)&T[d][c + 8];
    unsigned short* o = (unsigned short*)Vt + (size_t)(bh * 64 + d) * S_ + s0 + c;
    *(u16x8*)o = a;
    *(u16x8*)(o + 8) = bvv;
}

// ---------------------------------------------------------------------------
// Swapped-QK MFMA flash attention. 4 independent waves/block, 16 q-rows/wave.
// S^T = mfma(K_frag, Q_frag): lane holds 16 scores for q = lane&15
//   at keys kb*16 + (lane>>4)*4 + r  -> softmax is in-lane + 2 shfl.
// PV with key-permuted fragments (permutation applied to BOTH operands):
//   B-slot (lhi,j) of kc-MFMA covers key kc*32 + (j>>2)*16 + lhi*4 + (j&3),
//   which is lane's own p -> zero cross-lane exchange, no LDS.
// Output is O^T in C/D layout -> 8B stores.
// ---------------------------------------------------------------------------
__global__ __launch_bounds__(256) void attn_mfma(
    const __bf16* __restrict__ Q, const __bf16* __restrict__ Kf,
    const __bf16* __restrict__ Vt, __bf16* __restrict__ O) {
    const int tid = threadIdx.x;
    const int lane = tid & 63;
    const int w = tid >> 6;
    const int l15 = lane & 15, lhi = lane >> 4;
    const int q0 = blockIdx.x * 64 + w * 16;
    const int bb = blockIdx.y >> 4, hh = blockIdx.y & 15;

    // Q fragments (B-operand), pre-scaled by 1/8 (exact)
    bf16x8 qf[2];
    {
        const __bf16* qrow =
            Q + (size_t)(bb * S_ + q0 + l15) * E_ + hh * 64 + lhi * 8;
#pragma unroll
        for (int kc = 0; kc < 2; ++kc) {
            const u16x8 raw = *(const u16x8*)(qrow + kc * 32);
            bf16x8 v;
#pragma unroll
            for (int j = 0; j < 8; ++j) v[j] = (__bf16)(bf2f(raw[j]) * 0.125f);
            qf[kc] = v;
        }
    }
    const __bf16* kbase = Kf + (size_t)(bb * S_ + l15) * E_ + hh * 64 + lhi * 8;
    const __bf16* vbase = Vt + (size_t)(blockIdx.y * 64 + l15) * S_ + lhi * 4;

    float m_l = -1e30f, l_l = 0.f;
    f32x4 oacc[4] = {};

    for (int kt = 0; kt < S_ / 64; ++kt) {
        // K fragments (A-operand): rows = keys
        bf16x8 kfr[4][2];
#pragma unroll
        for (int kb = 0; kb < 4; ++kb)
#pragma unroll
            for (int kc = 0; kc < 2; ++kc)
                kfr[kb][kc] = *(const bf16x8*)(
                    kbase + (size_t)(kt * 64 + kb * 16) * E_ + kc * 32);
        // V^T fragments (A-operand), key-permuted: two 8B halves per frag
        bf16x8 vf[4][2];
#pragma unroll
        for (int db = 0; db < 4; ++db)
#pragma unroll
            for (int kc = 0; kc < 2; ++kc) {
                const __bf16* vp = vbase + (size_t)(db * 16) * S_ + kt * 64 + kc * 32;
                const bf16x4 lo = *(const bf16x4*)vp;
                const bf16x4 hi = *(const bf16x4*)(vp + 16);
                vf[db][kc] = __builtin_shufflevector(lo, hi, 0, 1, 2, 3, 4, 5, 6, 7);
            }
        // S^T[key][q]: col = q = l15, row(reg r, block kb) = kb*16 + lhi*4 + r
        f32x4 s[4] = {};
#pragma unroll
        for (int kb = 0; kb < 4; ++kb)
#pragma unroll
            for (int kc = 0; kc < 2; ++kc)
                s[kb] = __builtin_amdgcn_mfma_f32_16x16x32_bf16(
                    kfr[kb][kc], qf[kc], s[kb], 0, 0, 0);
        // lane-local softmax over 16 in-lane scores + 2-shfl cross-group
        float mx0 = fmaxf(fmaxf(s[0][0], s[0][1]), fmaxf(s[0][2], s[0][3]));
        float mx1 = fmaxf(fmaxf(s[1][0], s[1][1]), fmaxf(s[1][2], s[1][3]));
        float mx2 = fmaxf(fmaxf(s[2][0], s[2][1]), fmaxf(s[2][2], s[2][3]));
        float mx3 = fmaxf(fmaxf(s[3][0], s[3][1]), fmaxf(s[3][2], s[3][3]));
        float mx = fmaxf(fmaxf(mx0, mx1), fmaxf(mx2, mx3));
        mx = fmaxf(mx, __shfl_xor(mx, 16));
        mx = fmaxf(mx, __shfl_xor(mx, 32));
        const float mnew = fmaxf(m_l, mx);
        const float corr = __expf(m_l - mnew);
        float p[4][4];
        float rs = 0.f;
#pragma unroll
        for (int kb = 0; kb < 4; ++kb) {
            float sb = 0.f;
#pragma unroll
            for (int r = 0; r < 4; ++r) {
                p[kb][r] = __expf(s[kb][r] - mnew);
                sb += p[kb][r];
            }
            rs += sb;
        }
        rs += __shfl_xor(rs, 16);
        rs += __shfl_xor(rs, 32);
        l_l = l_l * corr + rs;
        m_l = mnew;
#pragma unroll
        for (int db = 0; db < 4; ++db)
#pragma unroll
            for (int r = 0; r < 4; ++r) oacc[db][r] *= corr;
        // pack P^T into B-fragments (in-lane, key-permuted to match vf)
        bf16x8 pf[2];
#pragma unroll
        for (int kc = 0; kc < 2; ++kc) {
            bf16x8 v;
#pragma unroll
            for (int r = 0; r < 4; ++r) {
                v[r] = (__bf16)p[kc * 2][r];
                v[r + 4] = (__bf16)p[kc * 2 + 1][r];
            }
            pf[kc] = v;
        }
#pragma unroll
        for (int db = 0; db < 4; ++db)
#pragma unroll
            for (int kc = 0; kc < 2; ++kc)
                oacc[db] = __builtin_amdgcn_mfma_f32_16x16x32_bf16(
                    vf[db][kc], pf[kc], oacc[db], 0, 0, 0);
    }
    // epilogue: O[q][d], lane holds O^T[d = db*16 + lhi*4 + r][q = l15]
    const float inv_l = 1.f / l_l;
    __bf16* orow = O + (size_t)(bb * S_ + q0 + l15) * E_ + hh * 64 + lhi * 4;
#pragma unroll
    for (int db = 0; db < 4; ++db) {
        bf16x4 ov;
#pragma unroll
        for (int r = 0; r < 4; ++r) ov[r] = (__bf16)(oacc[db][r] * inv_l);
        *(bf16x4*)(orow + db * 16) = ov;
    }
}

// ---------------------------------------------------------------------------
// out[m] = bf16 x[m,:] . f32 W_out + b_out -> f32. One wave per row.
// ---------------------------------------------------------------------------
__global__ __launch_bounds__(256) void final_proj(
    const __bf16* __restrict__ X, const float* __restrict__ Wout,
    const float* __restrict__ bout, float* __restrict__ out) {
    const int wid = threadIdx.x >> 6, lane = threadIdx.x & 63;
    const int m = blockIdx.x * 4 + wid;
    const __bf16* xrow = X + (size_t)m * E_;
    float acc = 0.f;
#pragma unroll
    for (int c = 0; c < 2; ++c) {
        const int idx = c * 512 + lane * 8;
        const u16x8 xv = *(const u16x8*)(xrow + idx);
        const float4 w1 = *(const float4*)(Wout + idx);
        const float4 w2 = *(const float4*)(Wout + idx + 4);
        acc += bf2f(xv[0]) * w1.x + bf2f(xv[1]) * w1.y + bf2f(xv[2]) * w1.z +
               bf2f(xv[3]) * w1.w + bf2f(xv[4]) * w2.x + bf2f(xv[5]) * w2.y +
               bf2f(xv[6]) * w2.z + bf2f(xv[7]) * w2.w;
    }
#pragma unroll
    for (int off = 32; off; off >>= 1) acc += __shfl_xor(acc, off, 64);
    if (lane == 0) out[m] = acc + bout[0];
}

extern "C" void kernel_launch(void* const* d_in, const int* in_sizes, int n_in,
                              void* d_out, int out_size, void* d_ws, size_t ws_size,
                              hipStream_t stream) {
    const int* item_inputs = (const int*)d_in[0];
    const int* skill_inputs = (const int*)d_in[1];
    const float* emb_item = (const float*)d_in[5];
    const float* emb_skill = (const float*)d_in[6];
    const float* W_in = (const float*)d_in[7];
    const float* b_in = (const float*)d_in[8];
    const float* Wq = (const float*)d_in[9];
    const float* bq = (const float*)d_in[10];
    const float* Wk = (const float*)d_in[11];
    const float* bk = (const float*)d_in[12];
    const float* Wv = (const float*)d_in[13];
    const float* bv = (const float*)d_in[14];
    // d_in[15] Wg, d_in[16] bg: softmax-invariant, skipped.
    const float* pos_key = (const float*)d_in[17];
    const float* Wl = (const float*)d_in[18];
    const float* bl = (const float*)d_in[19];
    const float* W_out = (const float*)d_in[20];
    const float* b_out = (const float*)d_in[21];
    float* out = (float*)d_out;

    const size_t SZ = (size_t)M_ * E_;  // 4M
    __bf16* Xc = (__bf16*)d_ws;         // 8M elems (dead after embed GEMM)
    __bf16* Vtb = Xc;                   // aliased: Vt [64][64][1024] = 4M elems
    __bf16* X = Xc + (size_t)M_ * 2048;
    __bf16* Qb = X + SZ;
    __bf16* Kb = Qb + SZ;
    __bf16* Vb = Kb + SZ;
    __bf16* Winb = Vb + SZ;             // 2M elems
    __bf16* Wbuf = Winb + 2 * EE;       // 6M elems

    const dim3 gg(E_ / 64, M_ / 128);  // (16, 32)
    const dim3 bb(256);

    embed_gather<<<dim3(M_), bb, 0, stream>>>(item_inputs, skill_inputs,
                                              emb_item, emb_skill, Xc);
    cvt_f32_bf16<<<dim3(2 * EE / 1024), bb, 0, stream>>>(W_in, Winb, 2 * EE);
    gemm_bf16<0, 0><<<gg, bb, 0, stream>>>(Xc, Winb, b_in, X, 2048, nullptr);

    for (int l = 0; l < L_; ++l) {
        cvt_layer_weights<<<dim3(6 * EE / 1024), bb, 0, stream>>>(
            Wq + (size_t)l * EE, Wk + (size_t)l * EE, Wv + (size_t)l * EE,
            Wl + (size_t)l * 3 * EE, Wbuf);
        const float* pe_l = pos_key + (size_t)l * S_ * D_;
        gemm_bf16<0, 0><<<gg, bb, 0, stream>>>(X, Wbuf + 0 * EE, bq + l * E_, Qb, E_, nullptr);
        gemm_bf16<0, 1><<<gg, bb, 0, stream>>>(Qb, Wbuf + 1 * EE, bk + l * E_, Kb, E_, pe_l);
        gemm_bf16<0, 0><<<gg, bb, 0, stream>>>(Qb, Wbuf + 2 * EE, bv + l * E_, Vb, E_, nullptr);
        v_transpose<<<dim3(S_ / 64, B_ * H_), bb, 0, stream>>>(Vb, Vtb);
        attn_mfma<<<dim3(S_ / 64, B_ * H_), bb, 0, stream>>>(Qb, Kb, Vtb, X);
        gemm_bf16<1, 0><<<gg, bb, 0, stream>>>(X, Wbuf + 3 * EE, bl + (l * 3 + 0) * E_, Qb, E_, nullptr);
        gemm_bf16<1, 0><<<gg, bb, 0, stream>>>(Qb, Wbuf + 4 * EE, bl + (l * 3 + 1) * E_, Kb, E_, nullptr);
        gemm_bf16<1, 0><<<gg, bb, 0, stream>>>(Kb, Wbuf + 5 * EE, bl + (l * 3 + 2) * E_, X, E_, nullptr);
    }
    final_proj<<<dim3(M_ / 4), bb, 0, stream>>>(X, W_out, b_out, out);
}

// Round 7
// 1065.386 us; speedup vs baseline: 1.2497x; 1.2497x over previous
//
#include <hip/hip_runtime.h>
#include <hip/hip_bf16.h>

// AKT forward, round 7: swapped-QK MFMA flash attention with PRODUCER-PACKED
// K/V fragment layouts (k-GEMM/v-GEMM epilogues write MFMA-fragment order, so
// every attn K/V load is a fully-coalesced 16B/lane read). No v_transpose.
//   - glo term dropped (softmax-invariant per-query constant)
//   - pos_key folded into k-GEMM epilogue
// Workspace: Xc[4096,2048]bf16 | X,Qb [4096,1024] | Kp,Vp packed 4M | W bufs

#define B_ 4
#define S_ 1024
#define E_ 1024
#define H_ 16
#define D_ 64
#define L_ 4
#define M_ (B_ * S_)  // 4096
#define EE (E_ * E_)  // 1M

typedef __attribute__((ext_vector_type(8))) __bf16 bf16x8;
typedef __attribute__((ext_vector_type(4))) __bf16 bf16x4;
typedef __attribute__((ext_vector_type(4))) float f32x4;
typedef __attribute__((ext_vector_type(8))) unsigned short u16x8;

__device__ __forceinline__ float bf2f(unsigned short u) {
    union { unsigned int i; float f; } x;
    x.i = ((unsigned int)u) << 16;
    return x.f;
}
__device__ __forceinline__ float gelu_exact(float x) {
    return 0.5f * x * (1.0f + erff(x * 0.70710678118654752f));
}

// Packed K layout: frag=((bh*16+kt)*4+kb)*2+kc, elem=lane*8+j with
//   lane = lhi*16 + l15, srow = kt*64+kb*16+l15, d = kc*32+lhi*8+j.
__device__ __forceinline__ size_t kpack_idx(int m, int col) {
    const int b = m >> 10, srow = m & (S_ - 1);
    const int h = col >> 6, d = col & 63;
    const int bh = b * H_ + h;
    const int kt = srow >> 6, kb = (srow >> 4) & 3, l15 = srow & 15;
    const int kc = d >> 5, lhi = (d >> 3) & 3, j = d & 7;
    const int frag = ((bh * 16 + kt) * 4 + kb) * 2 + kc;
    return (size_t)frag * 512 + (size_t)(lhi * 16 + l15) * 8 + j;
}
// Packed V layout (key-permuted to match P^T B-fragments): frag index uses
// db = d>>4; within frag, lane = lhi*16 + (d&15), j = ((kl>>4)<<2)|(kl&3),
// lhi = (kl>>2)&3 where kl = key&31, kc = (key>>5)&1, kt = key>>6.
__device__ __forceinline__ size_t vpack_idx(int m, int col) {
    const int b = m >> 10, key = m & (S_ - 1);
    const int h = col >> 6, d = col & 63;
    const int bh = b * H_ + h;
    const int kt = key >> 6;
    const int k6 = key & 63;
    const int kc = k6 >> 5, kl = k6 & 31;
    const int lhi = (kl >> 2) & 3;
    const int j = ((kl >> 4) << 2) | (kl & 3);
    const int db = d >> 4, l15 = d & 15;
    const int frag = ((bh * 16 + kt) * 4 + db) * 2 + kc;
    return (size_t)frag * 512 + (size_t)(lhi * 16 + l15) * 8 + j;
}

// ---------------------------------------------------------------------------
// f32 -> bf16 bulk convert
// ---------------------------------------------------------------------------
__global__ __launch_bounds__(256) void cvt_f32_bf16(
    const float* __restrict__ in, __bf16* __restrict__ out, int n) {
    const int i = (blockIdx.x * 256 + threadIdx.x) * 4;
    if (i >= n) return;
    const float4 v = *(const float4*)(in + i);
    __bf16* o = out + i;
    o[0] = (__bf16)v.x; o[1] = (__bf16)v.y; o[2] = (__bf16)v.z; o[3] = (__bf16)v.w;
}

// per-layer: Wq,Wk,Wv,Wl[0..2] (each 1M f32) -> Wbuf[6M] bf16
__global__ __launch_bounds__(256) void cvt_layer_weights(
    const float* __restrict__ Wq, const float* __restrict__ Wk,
    const float* __restrict__ Wv, const float* __restrict__ Wl,
    __bf16* __restrict__ out) {
    const int i = (blockIdx.x * 256 + threadIdx.x) * 4;  // < 6M
    const int mat = i >> 20;
    const int off = i & (EE - 1);
    const float* src = (mat == 0) ? Wq : (mat == 1) ? Wk : (mat == 2) ? Wv
                                        : Wl + (size_t)(mat - 3) * EE;
    const float4 v = *(const float4*)(src + off);
    __bf16* o = out + i;
    o[0] = (__bf16)v.x; o[1] = (__bf16)v.y; o[2] = (__bf16)v.z; o[3] = (__bf16)v.w;
}

// ---------------------------------------------------------------------------
// Xc[r, 0:2048] = bf16(concat(emb_item[item_idx[r]], emb_skill[skill_idx[r]]))
// ---------------------------------------------------------------------------
__global__ __launch_bounds__(256) void embed_gather(
    const int* __restrict__ item_idx, const int* __restrict__ skill_idx,
    const float* __restrict__ emb_item, const float* __restrict__ emb_skill,
    __bf16* __restrict__ Xc) {
    const int r = blockIdx.x;
    const int c = threadIdx.x * 8;
    const float* s = (c < E_) ? emb_item + (size_t)item_idx[r] * E_ + c
                              : emb_skill + (size_t)skill_idx[r] * E_ + (c - E_);
    const float4 a = *(const float4*)s;
    const float4 b = *(const float4*)(s + 4);
    __bf16* o = Xc + (size_t)r * 2048 + c;
    o[0] = (__bf16)a.x; o[1] = (__bf16)a.y; o[2] = (__bf16)a.z; o[3] = (__bf16)a.w;
    o[4] = (__bf16)b.x; o[5] = (__bf16)b.y; o[6] = (__bf16)b.z; o[7] = (__bf16)b.w;
}

// ---------------------------------------------------------------------------
// C = A[M_,K]bf16 * Bm[1024,K]bf16^T + bias(f32); opt GELU / pe-add.
// PACK: 0 = row-major C, 1 = K-fragment-packed, 2 = V-fragment-packed.
// BM=128, BN=64, BK=32. 256 threads = 4 waves (2x2), wave tile 64x32.
// ---------------------------------------------------------------------------
template <int ACT, int ADD_PE, int PACK>
__global__ __launch_bounds__(256) void gemm_bf16(
    const __bf16* __restrict__ A, const __bf16* __restrict__ Bm,
    const float* __restrict__ bias, __bf16* __restrict__ C, int K,
    const float* __restrict__ pe) {
    __shared__ __bf16 As[128 * 32];
    __shared__ __bf16 Bs[64 * 32];
    const int tid = threadIdx.x;
    const int lane = tid & 63;
    const int wid = tid >> 6;
    const int wm = wid >> 1;
    const int wn = wid & 1;
    const int m0 = blockIdx.y * 128;
    const int n0 = blockIdx.x * 64;

    const int ca0 = wid * 128 + lane;
    const int ca1 = ca0 + 64;
    const int cb = wid * 64 + lane;
    const int ra0 = ca0 >> 2, ga0 = (ca0 & 3) ^ (ra0 & 3);
    const int ra1 = ca1 >> 2, ga1 = (ca1 & 3) ^ (ra1 & 3);
    const int rb = cb >> 2, gb = (cb & 3) ^ (rb & 3);
    const __bf16* pa0 = A + (size_t)(m0 + ra0) * K + ga0 * 8;
    const __bf16* pa1 = A + (size_t)(m0 + ra1) * K + ga1 * 8;
    const __bf16* pb = Bm + (size_t)(n0 + rb) * K + gb * 8;
    __bf16* lda0 = As + (size_t)(wid * 128) * 8;
    __bf16* lda1 = As + (size_t)(wid * 128 + 64) * 8;
    __bf16* ldb = Bs + (size_t)(wid * 64) * 8;

    const int acg = lane >> 4;
    int aoff[4], boff[2];
#pragma unroll
    for (int mi = 0; mi < 4; ++mi) {
        const int row = wm * 64 + mi * 16 + (lane & 15);
        aoff[mi] = row * 32 + ((acg ^ (row & 3)) << 3);
    }
#pragma unroll
    for (int ni = 0; ni < 2; ++ni) {
        const int row = wn * 32 + ni * 16 + (lane & 15);
        boff[ni] = row * 32 + ((acg ^ (row & 3)) << 3);
    }

    f32x4 acc[4][2] = {};

    for (int k0 = 0; k0 < K; k0 += 32) {
        __builtin_amdgcn_global_load_lds(
            (const __attribute__((address_space(1))) unsigned int*)(pa0 + k0),
            (__attribute__((address_space(3))) unsigned int*)lda0, 16, 0, 0);
        __builtin_amdgcn_global_load_lds(
            (const __attribute__((address_space(1))) unsigned int*)(pa1 + k0),
            (__attribute__((address_space(3))) unsigned int*)lda1, 16, 0, 0);
        __builtin_amdgcn_global_load_lds(
            (const __attribute__((address_space(1))) unsigned int*)(pb + k0),
            (__attribute__((address_space(3))) unsigned int*)ldb, 16, 0, 0);
        __syncthreads();
        bf16x8 af[4], bfr[2];
#pragma unroll
        for (int mi = 0; mi < 4; ++mi) af[mi] = *(const bf16x8*)(As + aoff[mi]);
#pragma unroll
        for (int ni = 0; ni < 2; ++ni) bfr[ni] = *(const bf16x8*)(Bs + boff[ni]);
#pragma unroll
        for (int mi = 0; mi < 4; ++mi)
#pragma unroll
            for (int ni = 0; ni < 2; ++ni)
                acc[mi][ni] = __builtin_amdgcn_mfma_f32_16x16x32_bf16(
                    af[mi], bfr[ni], acc[mi][ni], 0, 0, 0);
        __syncthreads();
    }

    const int ccol0 = n0 + wn * 32 + (lane & 15);
    const int crow0 = m0 + wm * 64 + ((lane >> 4) << 2);
#pragma unroll
    for (int mi = 0; mi < 4; ++mi) {
#pragma unroll
        for (int ni = 0; ni < 2; ++ni) {
            const int col = ccol0 + ni * 16;
            const float bsum = bias[col];
#pragma unroll
            for (int r = 0; r < 4; ++r) {
                const int row = crow0 + mi * 16 + r;
                float v = acc[mi][ni][r] + bsum;
                if (ADD_PE) v += pe[((row & (S_ - 1)) << 6) + (col & (D_ - 1))];
                if (ACT) v = gelu_exact(v);
                if (PACK == 0)      C[(size_t)row * E_ + col] = (__bf16)v;
                else if (PACK == 1) C[kpack_idx(row, col)] = (__bf16)v;
                else                C[vpack_idx(row, col)] = (__bf16)v;
            }
        }
    }
}

// ---------------------------------------------------------------------------
// Swapped-QK MFMA flash attention, packed-K/V inputs (all loads coalesced).
// 4 independent waves/block, 16 q-rows/wave, no LDS, no barriers.
// S^T = mfma(K_frag, Q_frag): lane holds 16 scores for q = lane&15.
// PV with key-permuted fragments; P stays in registers. Output O^T 8B stores.
// ---------------------------------------------------------------------------
__global__ __launch_bounds__(256) void attn_mfma(
    const __bf16* __restrict__ Q, const __bf16* __restrict__ Kp,
    const __bf16* __restrict__ Vp, __bf16* __restrict__ O) {
    const int tid = threadIdx.x;
    const int lane = tid & 63;
    const int w = tid >> 6;
    const int l15 = lane & 15, lhi = lane >> 4;
    const int q0 = blockIdx.x * 64 + w * 16;
    const int bh = blockIdx.y;
    const int bb = bh >> 4, hh = bh & 15;

    // Q fragments (B-operand), pre-scaled by 1/8 (exact)
    bf16x8 qf[2];
    {
        const __bf16* qrow =
            Q + (size_t)(bb * S_ + q0 + l15) * E_ + hh * 64 + lhi * 8;
#pragma unroll
        for (int kc = 0; kc < 2; ++kc) {
            const u16x8 raw = *(const u16x8*)(qrow + kc * 32);
            bf16x8 v;
#pragma unroll
            for (int j = 0; j < 8; ++j) v[j] = (__bf16)(bf2f(raw[j]) * 0.125f);
            qf[kc] = v;
        }
    }
    const __bf16* kp = Kp + (size_t)bh * 16 * 8 * 512 + lane * 8;
    const __bf16* vp = Vp + (size_t)bh * 16 * 8 * 512 + lane * 8;

    float m_l = -1e30f, l_l = 0.f;
    f32x4 oacc[4] = {};

#pragma unroll 4
    for (int kt = 0; kt < S_ / 64; ++kt) {
        const __bf16* kpt = kp + (size_t)kt * 8 * 512;
        const __bf16* vpt = vp + (size_t)kt * 8 * 512;
        // K fragments (A-operand), fully coalesced
        bf16x8 kfr[4][2];
#pragma unroll
        for (int kb = 0; kb < 4; ++kb)
#pragma unroll
            for (int kc = 0; kc < 2; ++kc)
                kfr[kb][kc] = *(const bf16x8*)(kpt + (size_t)(kb * 2 + kc) * 512);
        // V^T fragments (A-operand), key-permuted, fully coalesced
        bf16x8 vf[4][2];
#pragma unroll
        for (int db = 0; db < 4; ++db)
#pragma unroll
            for (int kc = 0; kc < 2; ++kc)
                vf[db][kc] = *(const bf16x8*)(vpt + (size_t)(db * 2 + kc) * 512);
        // S^T[key][q]: col = q = l15, row(reg r, block kb) = kb*16 + lhi*4 + r
        f32x4 s[4] = {};
#pragma unroll
        for (int kb = 0; kb < 4; ++kb)
#pragma unroll
            for (int kc = 0; kc < 2; ++kc)
                s[kb] = __builtin_amdgcn_mfma_f32_16x16x32_bf16(
                    kfr[kb][kc], qf[kc], s[kb], 0, 0, 0);
        // lane-local softmax over 16 in-lane scores + 2-shfl cross-group
        float mx0 = fmaxf(fmaxf(s[0][0], s[0][1]), fmaxf(s[0][2], s[0][3]));
        float mx1 = fmaxf(fmaxf(s[1][0], s[1][1]), fmaxf(s[1][2], s[1][3]));
        float mx2 = fmaxf(fmaxf(s[2][0], s[2][1]), fmaxf(s[2][2], s[2][3]));
        float mx3 = fmaxf(fmaxf(s[3][0], s[3][1]), fmaxf(s[3][2], s[3][3]));
        float mx = fmaxf(fmaxf(mx0, mx1), fmaxf(mx2, mx3));
        mx = fmaxf(mx, __shfl_xor(mx, 16));
        mx = fmaxf(mx, __shfl_xor(mx, 32));
        const float mnew = fmaxf(m_l, mx);
        const float corr = __expf(m_l - mnew);
        float p[4][4];
        float rs = 0.f;
#pragma unroll
        for (int kb = 0; kb < 4; ++kb) {
            float sb = 0.f;
#pragma unroll
            for (int r = 0; r < 4; ++r) {
                p[kb][r] = __expf(s[kb][r] - mnew);
                sb += p[kb][r];
            }
            rs += sb;
        }
        rs += __shfl_xor(rs, 16);
        rs += __shfl_xor(rs, 32);
        l_l = l_l * corr + rs;
        m_l = mnew;
#pragma unroll
        for (int db = 0; db < 4; ++db)
#pragma unroll
            for (int r = 0; r < 4; ++r) oacc[db][r] *= corr;
        // pack P^T into B-fragments (in-lane, key-permuted to match vf)
        bf16x8 pf[2];
#pragma unroll
        for (int kc = 0; kc < 2; ++kc) {
            bf16x8 v;
#pragma unroll
            for (int r = 0; r < 4; ++r) {
                v[r] = (__bf16)p[kc * 2][r];
                v[r + 4] = (__bf16)p[kc * 2 + 1][r];
            }
            pf[kc] = v;
        }
#pragma unroll
        for (int db = 0; db < 4; ++db)
#pragma unroll
            for (int kc = 0; kc < 2; ++kc)
                oacc[db] = __builtin_amdgcn_mfma_f32_16x16x32_bf16(
                    vf[db][kc], pf[kc], oacc[db], 0, 0, 0);
    }
    // epilogue: O[q][d], lane holds O^T[d = db*16 + lhi*4 + r][q = l15]
    const float inv_l = 1.f / l_l;
    __bf16* orow = O + (size_t)(bb * S_ + q0 + l15) * E_ + hh * 64 + lhi * 4;
#pragma unroll
    for (int db = 0; db < 4; ++db) {
        bf16x4 ov;
#pragma unroll
        for (int r = 0; r < 4; ++r) ov[r] = (__bf16)(oacc[db][r] * inv_l);
        *(bf16x4*)(orow + db * 16) = ov;
    }
}

// ---------------------------------------------------------------------------
// out[m] = bf16 x[m,:] . f32 W_out + b_out -> f32. One wave per row.
// ---------------------------------------------------------------------------
__global__ __launch_bounds__(256) void final_proj(
    const __bf16* __restrict__ X, const float* __restrict__ Wout,
    const float* __restrict__ bout, float* __restrict__ out) {
    const int wid = threadIdx.x >> 6, lane = threadIdx.x & 63;
    const int m = blockIdx.x * 4 + wid;
    const __bf16* xrow = X + (size_t)m * E_;
    float acc = 0.f;
#pragma unroll
    for (int c = 0; c < 2; ++c) {
        const int idx = c * 512 + lane * 8;
        const u16x8 xv = *(const u16x8*)(xrow + idx);
        const float4 w1 = *(const float4*)(Wout + idx);
        const float4 w2 = *(const float4*)(Wout + idx + 4);
        acc += bf2f(xv[0]) * w1.x + bf2f(xv[1]) * w1.y + bf2f(xv[2]) * w1.z +
               bf2f(xv[3]) * w1.w + bf2f(xv[4]) * w2.x + bf2f(xv[5]) * w2.y +
               bf2f(xv[6]) * w2.z + bf2f(xv[7]) * w2.w;
    }
#pragma unroll
    for (int off = 32; off; off >>= 1) acc += __shfl_xor(acc, off, 64);
    if (lane == 0) out[m] = acc + bout[0];
}

extern "C" void kernel_launch(void* const* d_in, const int* in_sizes, int n_in,
                              void* d_out, int out_size, void* d_ws, size_t ws_size,
                              hipStream_t stream) {
    const int* item_inputs = (const int*)d_in[0];
    const int* skill_inputs = (const int*)d_in[1];
    const float* emb_item = (const float*)d_in[5];
    const float* emb_skill = (const float*)d_in[6];
    const float* W_in = (const float*)d_in[7];
    const float* b_in = (const float*)d_in[8];
    const float* Wq = (const float*)d_in[9];
    const float* bq = (const float*)d_in[10];
    const float* Wk = (const float*)d_in[11];
    const float* bk = (const float*)d_in[12];
    const float* Wv = (const float*)d_in[13];
    const float* bv = (const float*)d_in[14];
    // d_in[15] Wg, d_in[16] bg: softmax-invariant, skipped.
    const float* pos_key = (const float*)d_in[17];
    const float* Wl = (const float*)d_in[18];
    const float* bl = (const float*)d_in[19];
    const float* W_out = (const float*)d_in[20];
    const float* b_out = (const float*)d_in[21];
    float* out = (float*)d_out;

    const size_t SZ = (size_t)M_ * E_;  // 4M
    __bf16* Xc = (__bf16*)d_ws;         // 8M elems (dead after embed GEMM)
    __bf16* X = Xc + (size_t)M_ * 2048;
    __bf16* Qb = X + SZ;
    __bf16* Kp = Qb + SZ;               // packed K fragments, 4M elems
    __bf16* Vp = Kp + SZ;               // packed V fragments, 4M elems
    __bf16* Winb = Vp + SZ;             // 2M elems
    __bf16* Wbuf = Winb + 2 * EE;       // 6M elems

    const dim3 gg(E_ / 64, M_ / 128);  // (16, 32)
    const dim3 bb(256);

    embed_gather<<<dim3(M_), bb, 0, stream>>>(item_inputs, skill_inputs,
                                              emb_item, emb_skill, Xc);
    cvt_f32_bf16<<<dim3(2 * EE / 1024), bb, 0, stream>>>(W_in, Winb, 2 * EE);
    gemm_bf16<0, 0, 0><<<gg, bb, 0, stream>>>(Xc, Winb, b_in, X, 2048, nullptr);

    for (int l = 0; l < L_; ++l) {
        cvt_layer_weights<<<dim3(6 * EE / 1024), bb, 0, stream>>>(
            Wq + (size_t)l * EE, Wk + (size_t)l * EE, Wv + (size_t)l * EE,
            Wl + (size_t)l * 3 * EE, Wbuf);
        const float* pe_l = pos_key + (size_t)l * S_ * D_;
        gemm_bf16<0, 0, 0><<<gg, bb, 0, stream>>>(X, Wbuf + 0 * EE, bq + l * E_, Qb, E_, nullptr);
        gemm_bf16<0, 1, 1><<<gg, bb, 0, stream>>>(Qb, Wbuf + 1 * EE, bk + l * E_, Kp, E_, pe_l);
        gemm_bf16<0, 0, 2><<<gg, bb, 0, stream>>>(Qb, Wbuf + 2 * EE, bv + l * E_, Vp, E_, nullptr);
        attn_mfma<<<dim3(S_ / 64, B_ * H_), bb, 0, stream>>>(Qb, Kp, Vp, X);
        gemm_bf16<1, 0, 0><<<gg, bb, 0, stream>>>(X, Wbuf + 3 * EE, bl + (l * 3 + 0) * E_, Qb, E_, nullptr);
        gemm_bf16<1, 0, 0><<<gg, bb, 0, stream>>>(Qb, Wbuf + 4 * EE, bl + (l * 3 + 1) * E_, Kp, E_, nullptr);
        gemm_bf16<1, 0, 0><<<gg, bb, 0, stream>>>(Kp, Wbuf + 5 * EE, bl + (l * 3 + 2) * E_, X, E_, nullptr);
    }
    final_proj<<<dim3(M_ / 4), bb, 0, stream>>>(X, W_out, b_out, out);
}

// Round 8
// 747.022 us; speedup vs baseline: 1.7823x; 1.4262x over previous
//
#include <hip/hip_runtime.h>
#include <hip/hip_bf16.h>

// AKT forward, round 8: attn with LDS-staged K/V shared across 8 waves
// (128 q-rows/block), double-buffered global_load_lds prefetch (2-phase).
// K/V packed by producer GEMMs in MFMA-fragment order (identity LDS layout).
//   - glo term dropped (softmax-invariant per-query constant)
//   - pos_key folded into k-GEMM epilogue
// Workspace: Xc[4096,2048]bf16 | X,Qb [4096,1024] | Kp,Vp packed 4M | W bufs

#define B_ 4
#define S_ 1024
#define E_ 1024
#define H_ 16
#define D_ 64
#define L_ 4
#define M_ (B_ * S_)  // 4096
#define EE (E_ * E_)  // 1M

typedef __attribute__((ext_vector_type(8))) __bf16 bf16x8;
typedef __attribute__((ext_vector_type(4))) __bf16 bf16x4;
typedef __attribute__((ext_vector_type(4))) float f32x4;
typedef __attribute__((ext_vector_type(8))) unsigned short u16x8;

__device__ __forceinline__ float bf2f(unsigned short u) {
    union { unsigned int i; float f; } x;
    x.i = ((unsigned int)u) << 16;
    return x.f;
}
__device__ __forceinline__ float gelu_exact(float x) {
    return 0.5f * x * (1.0f + erff(x * 0.70710678118654752f));
}

// Packed K layout: frag=((bh*16+kt)*4+kb)*2+kc, elem=lane*8+j with
//   lane = lhi*16 + l15, srow = kt*64+kb*16+l15, d = kc*32+lhi*8+j.
__device__ __forceinline__ size_t kpack_idx(int m, int col) {
    const int b = m >> 10, srow = m & (S_ - 1);
    const int h = col >> 6, d = col & 63;
    const int bh = b * H_ + h;
    const int kt = srow >> 6, kb = (srow >> 4) & 3, l15 = srow & 15;
    const int kc = d >> 5, lhi = (d >> 3) & 3, j = d & 7;
    const int frag = ((bh * 16 + kt) * 4 + kb) * 2 + kc;
    return (size_t)frag * 512 + (size_t)(lhi * 16 + l15) * 8 + j;
}
// Packed V layout (key-permuted to match P^T B-fragments).
__device__ __forceinline__ size_t vpack_idx(int m, int col) {
    const int b = m >> 10, key = m & (S_ - 1);
    const int h = col >> 6, d = col & 63;
    const int bh = b * H_ + h;
    const int kt = key >> 6;
    const int k6 = key & 63;
    const int kc = k6 >> 5, kl = k6 & 31;
    const int lhi = (kl >> 2) & 3;
    const int j = ((kl >> 4) << 2) | (kl & 3);
    const int db = d >> 4, l15 = d & 15;
    const int frag = ((bh * 16 + kt) * 4 + db) * 2 + kc;
    return (size_t)frag * 512 + (size_t)(lhi * 16 + l15) * 8 + j;
}

// ---------------------------------------------------------------------------
// f32 -> bf16 bulk convert
// ---------------------------------------------------------------------------
__global__ __launch_bounds__(256) void cvt_f32_bf16(
    const float* __restrict__ in, __bf16* __restrict__ out, int n) {
    const int i = (blockIdx.x * 256 + threadIdx.x) * 4;
    if (i >= n) return;
    const float4 v = *(const float4*)(in + i);
    __bf16* o = out + i;
    o[0] = (__bf16)v.x; o[1] = (__bf16)v.y; o[2] = (__bf16)v.z; o[3] = (__bf16)v.w;
}

// per-layer: Wq,Wk,Wv,Wl[0..2] (each 1M f32) -> Wbuf[6M] bf16
__global__ __launch_bounds__(256) void cvt_layer_weights(
    const float* __restrict__ Wq, const float* __restrict__ Wk,
    const float* __restrict__ Wv, const float* __restrict__ Wl,
    __bf16* __restrict__ out) {
    const int i = (blockIdx.x * 256 + threadIdx.x) * 4;  // < 6M
    const int mat = i >> 20;
    const int off = i & (EE - 1);
    const float* src = (mat == 0) ? Wq : (mat == 1) ? Wk : (mat == 2) ? Wv
                                        : Wl + (size_t)(mat - 3) * EE;
    const float4 v = *(const float4*)(src + off);
    __bf16* o = out + i;
    o[0] = (__bf16)v.x; o[1] = (__bf16)v.y; o[2] = (__bf16)v.z; o[3] = (__bf16)v.w;
}

// ---------------------------------------------------------------------------
// Xc[r, 0:2048] = bf16(concat(emb_item[item_idx[r]], emb_skill[skill_idx[r]]))
// ---------------------------------------------------------------------------
__global__ __launch_bounds__(256) void embed_gather(
    const int* __restrict__ item_idx, const int* __restrict__ skill_idx,
    const float* __restrict__ emb_item, const float* __restrict__ emb_skill,
    __bf16* __restrict__ Xc) {
    const int r = blockIdx.x;
    const int c = threadIdx.x * 8;
    const float* s = (c < E_) ? emb_item + (size_t)item_idx[r] * E_ + c
                              : emb_skill + (size_t)skill_idx[r] * E_ + (c - E_);
    const float4 a = *(const float4*)s;
    const float4 b = *(const float4*)(s + 4);
    __bf16* o = Xc + (size_t)r * 2048 + c;
    o[0] = (__bf16)a.x; o[1] = (__bf16)a.y; o[2] = (__bf16)a.z; o[3] = (__bf16)a.w;
    o[4] = (__bf16)b.x; o[5] = (__bf16)b.y; o[6] = (__bf16)b.z; o[7] = (__bf16)b.w;
}

// ---------------------------------------------------------------------------
// C = A[M_,K]bf16 * Bm[1024,K]bf16^T + bias(f32); opt GELU / pe-add.
// PACK: 0 = row-major C, 1 = K-fragment-packed, 2 = V-fragment-packed.
// BM=128, BN=64, BK=32. 256 threads = 4 waves (2x2), wave tile 64x32.
// ---------------------------------------------------------------------------
template <int ACT, int ADD_PE, int PACK>
__global__ __launch_bounds__(256) void gemm_bf16(
    const __bf16* __restrict__ A, const __bf16* __restrict__ Bm,
    const float* __restrict__ bias, __bf16* __restrict__ C, int K,
    const float* __restrict__ pe) {
    __shared__ __bf16 As[128 * 32];
    __shared__ __bf16 Bs[64 * 32];
    const int tid = threadIdx.x;
    const int lane = tid & 63;
    const int wid = tid >> 6;
    const int wm = wid >> 1;
    const int wn = wid & 1;
    const int m0 = blockIdx.y * 128;
    const int n0 = blockIdx.x * 64;

    const int ca0 = wid * 128 + lane;
    const int ca1 = ca0 + 64;
    const int cb = wid * 64 + lane;
    const int ra0 = ca0 >> 2, ga0 = (ca0 & 3) ^ (ra0 & 3);
    const int ra1 = ca1 >> 2, ga1 = (ca1 & 3) ^ (ra1 & 3);
    const int rb = cb >> 2, gb = (cb & 3) ^ (rb & 3);
    const __bf16* pa0 = A + (size_t)(m0 + ra0) * K + ga0 * 8;
    const __bf16* pa1 = A + (size_t)(m0 + ra1) * K + ga1 * 8;
    const __bf16* pb = Bm + (size_t)(n0 + rb) * K + gb * 8;
    __bf16* lda0 = As + (size_t)(wid * 128) * 8;
    __bf16* lda1 = As + (size_t)(wid * 128 + 64) * 8;
    __bf16* ldb = Bs + (size_t)(wid * 64) * 8;

    const int acg = lane >> 4;
    int aoff[4], boff[2];
#pragma unroll
    for (int mi = 0; mi < 4; ++mi) {
        const int row = wm * 64 + mi * 16 + (lane & 15);
        aoff[mi] = row * 32 + ((acg ^ (row & 3)) << 3);
    }
#pragma unroll
    for (int ni = 0; ni < 2; ++ni) {
        const int row = wn * 32 + ni * 16 + (lane & 15);
        boff[ni] = row * 32 + ((acg ^ (row & 3)) << 3);
    }

    f32x4 acc[4][2] = {};

    for (int k0 = 0; k0 < K; k0 += 32) {
        __builtin_amdgcn_global_load_lds(
            (const __attribute__((address_space(1))) unsigned int*)(pa0 + k0),
            (__attribute__((address_space(3))) unsigned int*)lda0, 16, 0, 0);
        __builtin_amdgcn_global_load_lds(
            (const __attribute__((address_space(1))) unsigned int*)(pa1 + k0),
            (__attribute__((address_space(3))) unsigned int*)lda1, 16, 0, 0);
        __builtin_amdgcn_global_load_lds(
            (const __attribute__((address_space(1))) unsigned int*)(pb + k0),
            (__attribute__((address_space(3))) unsigned int*)ldb, 16, 0, 0);
        __syncthreads();
        bf16x8 af[4], bfr[2];
#pragma unroll
        for (int mi = 0; mi < 4; ++mi) af[mi] = *(const bf16x8*)(As + aoff[mi]);
#pragma unroll
        for (int ni = 0; ni < 2; ++ni) bfr[ni] = *(const bf16x8*)(Bs + boff[ni]);
#pragma unroll
        for (int mi = 0; mi < 4; ++mi)
#pragma unroll
            for (int ni = 0; ni < 2; ++ni)
                acc[mi][ni] = __builtin_amdgcn_mfma_f32_16x16x32_bf16(
                    af[mi], bfr[ni], acc[mi][ni], 0, 0, 0);
        __syncthreads();
    }

    const int ccol0 = n0 + wn * 32 + (lane & 15);
    const int crow0 = m0 + wm * 64 + ((lane >> 4) << 2);
#pragma unroll
    for (int mi = 0; mi < 4; ++mi) {
#pragma unroll
        for (int ni = 0; ni < 2; ++ni) {
            const int col = ccol0 + ni * 16;
            const float bsum = bias[col];
#pragma unroll
            for (int r = 0; r < 4; ++r) {
                const int row = crow0 + mi * 16 + r;
                float v = acc[mi][ni][r] + bsum;
                if (ADD_PE) v += pe[((row & (S_ - 1)) << 6) + (col & (D_ - 1))];
                if (ACT) v = gelu_exact(v);
                if (PACK == 0)      C[(size_t)row * E_ + col] = (__bf16)v;
                else if (PACK == 1) C[kpack_idx(row, col)] = (__bf16)v;
                else                C[vpack_idx(row, col)] = (__bf16)v;
            }
        }
    }
}

// ---------------------------------------------------------------------------
// Swapped-QK MFMA flash attention, LDS-staged K/V shared by 8 waves.
// Block = 8 waves x 16 q-rows = 128 q-rows. KV tile = 64 keys.
// Double-buffered LDS (2 x 16 KB); stage(kt+1) issued right after the
// barrier so the next barrier's vmcnt drain is the prefetch wait.
// ---------------------------------------------------------------------------
__global__ __launch_bounds__(512) void attn_mfma(
    const __bf16* __restrict__ Q, const __bf16* __restrict__ Kp,
    const __bf16* __restrict__ Vp, __bf16* __restrict__ O) {
    __shared__ __bf16 Slds[2][2][8 * 512];  // [buf][K/V][frag*512] = 32 KB
    const int tid = threadIdx.x;
    const int lane = tid & 63;
    const int w = tid >> 6;  // 0..7
    const int l15 = lane & 15, lhi = lane >> 4;
    const int q0 = blockIdx.x * 128 + w * 16;
    const int bh = blockIdx.y;
    const int bb = bh >> 4, hh = bh & 15;

    // Q fragments (B-operand), pre-scaled by 1/8 (exact)
    bf16x8 qf[2];
    {
        const __bf16* qrow =
            Q + (size_t)(bb * S_ + q0 + l15) * E_ + hh * 64 + lhi * 8;
#pragma unroll
        for (int kc = 0; kc < 2; ++kc) {
            const u16x8 raw = *(const u16x8*)(qrow + kc * 32);
            bf16x8 v;
#pragma unroll
            for (int j = 0; j < 8; ++j) v[j] = (__bf16)(bf2f(raw[j]) * 0.125f);
            qf[kc] = v;
        }
    }

    // wave w stages fragment w of K and of V for tile kt into buf
    const __bf16* kpw = Kp + ((size_t)bh * 16 * 8 + w) * 512 + lane * 8;
    const __bf16* vpw = Vp + ((size_t)bh * 16 * 8 + w) * 512 + lane * 8;

    float m_l = -1e30f, l_l = 0.f;
    f32x4 oacc[4] = {};

    // prologue: stage kt=0 into buf 0
    __builtin_amdgcn_global_load_lds(
        (const __attribute__((address_space(1))) unsigned int*)(kpw),
        (__attribute__((address_space(3))) unsigned int*)(&Slds[0][0][w * 512]),
        16, 0, 0);
    __builtin_amdgcn_global_load_lds(
        (const __attribute__((address_space(1))) unsigned int*)(vpw),
        (__attribute__((address_space(3))) unsigned int*)(&Slds[0][1][w * 512]),
        16, 0, 0);

#pragma unroll 2
    for (int kt = 0; kt < S_ / 64; ++kt) {
        const int cur = kt & 1;
        __syncthreads();  // drains vmcnt: buf[cur] staging complete, all waves
        if (kt < S_ / 64 - 1) {
            const size_t fo = (size_t)(kt + 1) * 8 * 512;
            __builtin_amdgcn_global_load_lds(
                (const __attribute__((address_space(1))) unsigned int*)(kpw + fo),
                (__attribute__((address_space(3))) unsigned int*)(
                    &Slds[cur ^ 1][0][w * 512]), 16, 0, 0);
            __builtin_amdgcn_global_load_lds(
                (const __attribute__((address_space(1))) unsigned int*)(vpw + fo),
                (__attribute__((address_space(3))) unsigned int*)(
                    &Slds[cur ^ 1][1][w * 512]), 16, 0, 0);
        }
        const __bf16* kl = &Slds[cur][0][0];
        const __bf16* vl = &Slds[cur][1][0];
        // S^T = mfma(K_frag, Q_frag): col = q = l15, row = kb*16 + lhi*4 + r
        f32x4 s[4];
#pragma unroll
        for (int kb = 0; kb < 4; ++kb) {
            const bf16x8 k0 = *(const bf16x8*)(kl + (kb * 2 + 0) * 512 + lane * 8);
            const bf16x8 k1 = *(const bf16x8*)(kl + (kb * 2 + 1) * 512 + lane * 8);
            f32x4 z = {};
            z = __builtin_amdgcn_mfma_f32_16x16x32_bf16(k0, qf[0], z, 0, 0, 0);
            s[kb] = __builtin_amdgcn_mfma_f32_16x16x32_bf16(k1, qf[1], z, 0, 0, 0);
        }
        // lane-local softmax over 16 in-lane scores + 2-shfl cross-group
        float mx0 = fmaxf(fmaxf(s[0][0], s[0][1]), fmaxf(s[0][2], s[0][3]));
        float mx1 = fmaxf(fmaxf(s[1][0], s[1][1]), fmaxf(s[1][2], s[1][3]));
        float mx2 = fmaxf(fmaxf(s[2][0], s[2][1]), fmaxf(s[2][2], s[2][3]));
        float mx3 = fmaxf(fmaxf(s[3][0], s[3][1]), fmaxf(s[3][2], s[3][3]));
        float mx = fmaxf(fmaxf(mx0, mx1), fmaxf(mx2, mx3));
        mx = fmaxf(mx, __shfl_xor(mx, 16));
        mx = fmaxf(mx, __shfl_xor(mx, 32));
        const float mnew = fmaxf(m_l, mx);
        const float corr = __expf(m_l - mnew);
        float p[4][4];
        float rs = 0.f;
#pragma unroll
        for (int kb = 0; kb < 4; ++kb) {
            float sb = 0.f;
#pragma unroll
            for (int r = 0; r < 4; ++r) {
                p[kb][r] = __expf(s[kb][r] - mnew);
                sb += p[kb][r];
            }
            rs += sb;
        }
        rs += __shfl_xor(rs, 16);
        rs += __shfl_xor(rs, 32);
        l_l = l_l * corr + rs;
        m_l = mnew;
#pragma unroll
        for (int db = 0; db < 4; ++db)
#pragma unroll
            for (int r = 0; r < 4; ++r) oacc[db][r] *= corr;
        // pack P^T into B-fragments (in-lane, key-permuted to match Vp)
        bf16x8 pf[2];
#pragma unroll
        for (int kc = 0; kc < 2; ++kc) {
            bf16x8 v;
#pragma unroll
            for (int r = 0; r < 4; ++r) {
                v[r] = (__bf16)p[kc * 2][r];
                v[r + 4] = (__bf16)p[kc * 2 + 1][r];
            }
            pf[kc] = v;
        }
#pragma unroll
        for (int db = 0; db < 4; ++db) {
            const bf16x8 v0 = *(const bf16x8*)(vl + (db * 2 + 0) * 512 + lane * 8);
            const bf16x8 v1 = *(const bf16x8*)(vl + (db * 2 + 1) * 512 + lane * 8);
            oacc[db] = __builtin_amdgcn_mfma_f32_16x16x32_bf16(v0, pf[0], oacc[db], 0, 0, 0);
            oacc[db] = __builtin_amdgcn_mfma_f32_16x16x32_bf16(v1, pf[1], oacc[db], 0, 0, 0);
        }
    }
    // epilogue: O[q][d], lane holds O^T[d = db*16 + lhi*4 + r][q = l15]
    const float inv_l = 1.f / l_l;
    __bf16* orow = O + (size_t)(bb * S_ + q0 + l15) * E_ + hh * 64 + lhi * 4;
#pragma unroll
    for (int db = 0; db < 4; ++db) {
        bf16x4 ov;
#pragma unroll
        for (int r = 0; r < 4; ++r) ov[r] = (__bf16)(oacc[db][r] * inv_l);
        *(bf16x4*)(orow + db * 16) = ov;
    }
}

// ---------------------------------------------------------------------------
// out[m] = bf16 x[m,:] . f32 W_out + b_out -> f32. One wave per row.
// ---------------------------------------------------------------------------
__global__ __launch_bounds__(256) void final_proj(
    const __bf16* __restrict__ X, const float* __restrict__ Wout,
    const float* __restrict__ bout, float* __restrict__ out) {
    const int wid = threadIdx.x >> 6, lane = threadIdx.x & 63;
    const int m = blockIdx.x * 4 + wid;
    const __bf16* xrow = X + (size_t)m * E_;
    float acc = 0.f;
#pragma unroll
    for (int c = 0; c < 2; ++c) {
        const int idx = c * 512 + lane * 8;
        const u16x8 xv = *(const u16x8*)(xrow + idx);
        const float4 w1 = *(const float4*)(Wout + idx);
        const float4 w2 = *(const float4*)(Wout + idx + 4);
        acc += bf2f(xv[0]) * w1.x + bf2f(xv[1]) * w1.y + bf2f(xv[2]) * w1.z +
               bf2f(xv[3]) * w1.w + bf2f(xv[4]) * w2.x + bf2f(xv[5]) * w2.y +
               bf2f(xv[6]) * w2.z + bf2f(xv[7]) * w2.w;
    }
#pragma unroll
    for (int off = 32; off; off >>= 1) acc += __shfl_xor(acc, off, 64);
    if (lane == 0) out[m] = acc + bout[0];
}

extern "C" void kernel_launch(void* const* d_in, const int* in_sizes, int n_in,
                              void* d_out, int out_size, void* d_ws, size_t ws_size,
                              hipStream_t stream) {
    const int* item_inputs = (const int*)d_in[0];
    const int* skill_inputs = (const int*)d_in[1];
    const float* emb_item = (const float*)d_in[5];
    const float* emb_skill = (const float*)d_in[6];
    const float* W_in = (const float*)d_in[7];
    const float* b_in = (const float*)d_in[8];
    const float* Wq = (const float*)d_in[9];
    const float* bq = (const float*)d_in[10];
    const float* Wk = (const float*)d_in[11];
    const float* bk = (const float*)d_in[12];
    const float* Wv = (const float*)d_in[13];
    const float* bv = (const float*)d_in[14];
    // d_in[15] Wg, d_in[16] bg: softmax-invariant, skipped.
    const float* pos_key = (const float*)d_in[17];
    const float* Wl = (const float*)d_in[18];
    const float* bl = (const float*)d_in[19];
    const float* W_out = (const float*)d_in[20];
    const float* b_out = (const float*)d_in[21];
    float* out = (float*)d_out;

    const size_t SZ = (size_t)M_ * E_;  // 4M
    __bf16* Xc = (__bf16*)d_ws;         // 8M elems (dead after embed GEMM)
    __bf16* X = Xc + (size_t)M_ * 2048;
    __bf16* Qb = X + SZ;
    __bf16* Kp = Qb + SZ;               // packed K fragments, 4M elems
    __bf16* Vp = Kp + SZ;               // packed V fragments, 4M elems
    __bf16* Winb = Vp + SZ;             // 2M elems
    __bf16* Wbuf = Winb + 2 * EE;       // 6M elems

    const dim3 gg(E_ / 64, M_ / 128);  // (16, 32)
    const dim3 bb(256);

    embed_gather<<<dim3(M_), bb, 0, stream>>>(item_inputs, skill_inputs,
                                              emb_item, emb_skill, Xc);
    cvt_f32_bf16<<<dim3(2 * EE / 1024), bb, 0, stream>>>(W_in, Winb, 2 * EE);
    gemm_bf16<0, 0, 0><<<gg, bb, 0, stream>>>(Xc, Winb, b_in, X, 2048, nullptr);

    for (int l = 0; l < L_; ++l) {
        cvt_layer_weights<<<dim3(6 * EE / 1024), bb, 0, stream>>>(
            Wq + (size_t)l * EE, Wk + (size_t)l * EE, Wv + (size_t)l * EE,
            Wl + (size_t)l * 3 * EE, Wbuf);
        const float* pe_l = pos_key + (size_t)l * S_ * D_;
        gemm_bf16<0, 0, 0><<<gg, bb, 0, stream>>>(X, Wbuf + 0 * EE, bq + l * E_, Qb, E_, nullptr);
        gemm_bf16<0, 1, 1><<<gg, bb, 0, stream>>>(Qb, Wbuf + 1 * EE, bk + l * E_, Kp, E_, pe_l);
        gemm_bf16<0, 0, 2><<<gg, bb, 0, stream>>>(Qb, Wbuf + 2 * EE, bv + l * E_, Vp, E_, nullptr);
        attn_mfma<<<dim3(S_ / 128, B_ * H_), dim3(512), 0, stream>>>(Qb, Kp, Vp, X);
        gemm_bf16<1, 0, 0><<<gg, bb, 0, stream>>>(X, Wbuf + 3 * EE, bl + (l * 3 + 0) * E_, Qb, E_, nullptr);
        gemm_bf16<1, 0, 0><<<gg, bb, 0, stream>>>(Qb, Wbuf + 4 * EE, bl + (l * 3 + 1) * E_, Kp, E_, nullptr);
        gemm_bf16<1, 0, 0><<<gg, bb, 0, stream>>>(Kp, Wbuf + 5 * EE, bl + (l * 3 + 2) * E_, X, E_, nullptr);
    }
    final_proj<<<dim3(M_ / 4), bb, 0, stream>>>(X, W_out, b_out, out);
}

// Round 9
// 672.833 us; speedup vs baseline: 1.9788x; 1.1103x over previous
//
#include <hip/hip_runtime.h>
#include <hip/hip_bf16.h>

// AKT forward, round 9: XCD-chunked block swizzle on GEMM + attn grids
// (fixes 8x A-panel / K-V over-fetch across XCD L2s), k|v fused GEMM (N=2048).
//   - glo term dropped (softmax-invariant per-query constant)
//   - pos_key folded into k-GEMM epilogue
// Workspace: Xc[4096,2048]bf16 | X,Qb [4096,1024] | Kp,Vp packed 4M | W bufs

#define B_ 4
#define S_ 1024
#define E_ 1024
#define H_ 16
#define D_ 64
#define L_ 4
#define M_ (B_ * S_)  // 4096
#define EE (E_ * E_)  // 1M

typedef __attribute__((ext_vector_type(8))) __bf16 bf16x8;
typedef __attribute__((ext_vector_type(4))) __bf16 bf16x4;
typedef __attribute__((ext_vector_type(4))) float f32x4;
typedef __attribute__((ext_vector_type(8))) unsigned short u16x8;

__device__ __forceinline__ float bf2f(unsigned short u) {
    union { unsigned int i; float f; } x;
    x.i = ((unsigned int)u) << 16;
    return x.f;
}
__device__ __forceinline__ float gelu_exact(float x) {
    return 0.5f * x * (1.0f + erff(x * 0.70710678118654752f));
}

// Packed K layout: frag=((bh*16+kt)*4+kb)*2+kc, elem=lane*8+j with
//   lane = lhi*16 + l15, srow = kt*64+kb*16+l15, d = kc*32+lhi*8+j.
__device__ __forceinline__ size_t kpack_idx(int m, int col) {
    const int b = m >> 10, srow = m & (S_ - 1);
    const int h = col >> 6, d = col & 63;
    const int bh = b * H_ + h;
    const int kt = srow >> 6, kb = (srow >> 4) & 3, l15 = srow & 15;
    const int kc = d >> 5, lhi = (d >> 3) & 3, j = d & 7;
    const int frag = ((bh * 16 + kt) * 4 + kb) * 2 + kc;
    return (size_t)frag * 512 + (size_t)(lhi * 16 + l15) * 8 + j;
}
// Packed V layout (key-permuted to match P^T B-fragments).
__device__ __forceinline__ size_t vpack_idx(int m, int col) {
    const int b = m >> 10, key = m & (S_ - 1);
    const int h = col >> 6, d = col & 63;
    const int bh = b * H_ + h;
    const int kt = key >> 6;
    const int k6 = key & 63;
    const int kc = k6 >> 5, kl = k6 & 31;
    const int lhi = (kl >> 2) & 3;
    const int j = ((kl >> 4) << 2) | (kl & 3);
    const int db = d >> 4, l15 = d & 15;
    const int frag = ((bh * 16 + kt) * 4 + db) * 2 + kc;
    return (size_t)frag * 512 + (size_t)(lhi * 16 + l15) * 8 + j;
}

// ---------------------------------------------------------------------------
// f32 -> bf16 bulk convert
// ---------------------------------------------------------------------------
__global__ __launch_bounds__(256) void cvt_f32_bf16(
    const float* __restrict__ in, __bf16* __restrict__ out, int n) {
    const int i = (blockIdx.x * 256 + threadIdx.x) * 4;
    if (i >= n) return;
    const float4 v = *(const float4*)(in + i);
    __bf16* o = out + i;
    o[0] = (__bf16)v.x; o[1] = (__bf16)v.y; o[2] = (__bf16)v.z; o[3] = (__bf16)v.w;
}

// per-layer: Wq,Wk,Wv,Wl[0..2] (each 1M f32) -> Wbuf[6M] bf16
__global__ __launch_bounds__(256) void cvt_layer_weights(
    const float* __restrict__ Wq, const float* __restrict__ Wk,
    const float* __restrict__ Wv, const float* __restrict__ Wl,
    __bf16* __restrict__ out) {
    const int i = (blockIdx.x * 256 + threadIdx.x) * 4;  // < 6M
    const int mat = i >> 20;
    const int off = i & (EE - 1);
    const float* src = (mat == 0) ? Wq : (mat == 1) ? Wk : (mat == 2) ? Wv
                                        : Wl + (size_t)(mat - 3) * EE;
    const float4 v = *(const float4*)(src + off);
    __bf16* o = out + i;
    o[0] = (__bf16)v.x; o[1] = (__bf16)v.y; o[2] = (__bf16)v.z; o[3] = (__bf16)v.w;
}

// ---------------------------------------------------------------------------
// Xc[r, 0:2048] = bf16(concat(emb_item[item_idx[r]], emb_skill[skill_idx[r]]))
// ---------------------------------------------------------------------------
__global__ __launch_bounds__(256) void embed_gather(
    const int* __restrict__ item_idx, const int* __restrict__ skill_idx,
    const float* __restrict__ emb_item, const float* __restrict__ emb_skill,
    __bf16* __restrict__ Xc) {
    const int r = blockIdx.x;
    const int c = threadIdx.x * 8;
    const float* s = (c < E_) ? emb_item + (size_t)item_idx[r] * E_ + c
                              : emb_skill + (size_t)skill_idx[r] * E_ + (c - E_);
    const float4 a = *(const float4*)s;
    const float4 b = *(const float4*)(s + 4);
    __bf16* o = Xc + (size_t)r * 2048 + c;
    o[0] = (__bf16)a.x; o[1] = (__bf16)a.y; o[2] = (__bf16)a.z; o[3] = (__bf16)a.w;
    o[4] = (__bf16)b.x; o[5] = (__bf16)b.y; o[6] = (__bf16)b.z; o[7] = (__bf16)b.w;
}

// ---------------------------------------------------------------------------
// C = A[M_,K]bf16 * Bm[N,K]bf16^T + bias(f32); opt GELU / pe-add.
// PACK: 0 = row-major C; 1 = K-packed; 2 = V-packed; 3 = fused k|v (N=2048,
//   cols<1024 -> K-packed + pe + bias, cols>=1024 -> V-packed + bias2).
// BM=128, BN=64, BK=32. 256 threads = 4 waves (2x2), wave tile 64x32.
// XCD-chunked block swizzle: each XCD gets a contiguous range of block ids.
// ---------------------------------------------------------------------------
template <int ACT, int ADD_PE, int PACK>
__global__ __launch_bounds__(256) void gemm_bf16(
    const __bf16* __restrict__ A, const __bf16* __restrict__ Bm,
    const float* __restrict__ bias, __bf16* __restrict__ C, int K,
    const float* __restrict__ pe, const float* __restrict__ bias2) {
    __shared__ __bf16 As[128 * 32];
    __shared__ __bf16 Bs[64 * 32];
    const int tid = threadIdx.x;
    const int lane = tid & 63;
    const int wid = tid >> 6;
    const int wm = wid >> 1;
    const int wn = wid & 1;

    // XCD-chunked bijective swizzle (nwg % 8 == 0 for all grids used)
    const int gx = gridDim.x;
    const int id = blockIdx.y * gx + blockIdx.x;
    const int nwg = gx * gridDim.y;
    const int swz = (id & 7) * (nwg >> 3) + (id >> 3);
    const int m0 = (swz / gx) * 128;
    const int n0 = (swz % gx) * 64;

    const int ca0 = wid * 128 + lane;
    const int ca1 = ca0 + 64;
    const int cb = wid * 64 + lane;
    const int ra0 = ca0 >> 2, ga0 = (ca0 & 3) ^ (ra0 & 3);
    const int ra1 = ca1 >> 2, ga1 = (ca1 & 3) ^ (ra1 & 3);
    const int rb = cb >> 2, gb = (cb & 3) ^ (rb & 3);
    const __bf16* pa0 = A + (size_t)(m0 + ra0) * K + ga0 * 8;
    const __bf16* pa1 = A + (size_t)(m0 + ra1) * K + ga1 * 8;
    const __bf16* pb = Bm + (size_t)(n0 + rb) * K + gb * 8;
    __bf16* lda0 = As + (size_t)(wid * 128) * 8;
    __bf16* lda1 = As + (size_t)(wid * 128 + 64) * 8;
    __bf16* ldb = Bs + (size_t)(wid * 64) * 8;

    const int acg = lane >> 4;
    int aoff[4], boff[2];
#pragma unroll
    for (int mi = 0; mi < 4; ++mi) {
        const int row = wm * 64 + mi * 16 + (lane & 15);
        aoff[mi] = row * 32 + ((acg ^ (row & 3)) << 3);
    }
#pragma unroll
    for (int ni = 0; ni < 2; ++ni) {
        const int row = wn * 32 + ni * 16 + (lane & 15);
        boff[ni] = row * 32 + ((acg ^ (row & 3)) << 3);
    }

    f32x4 acc[4][2] = {};

    for (int k0 = 0; k0 < K; k0 += 32) {
        __builtin_amdgcn_global_load_lds(
            (const __attribute__((address_space(1))) unsigned int*)(pa0 + k0),
            (__attribute__((address_space(3))) unsigned int*)lda0, 16, 0, 0);
        __builtin_amdgcn_global_load_lds(
            (const __attribute__((address_space(1))) unsigned int*)(pa1 + k0),
            (__attribute__((address_space(3))) unsigned int*)lda1, 16, 0, 0);
        __builtin_amdgcn_global_load_lds(
            (const __attribute__((address_space(1))) unsigned int*)(pb + k0),
            (__attribute__((address_space(3))) unsigned int*)ldb, 16, 0, 0);
        __syncthreads();
        bf16x8 af[4], bfr[2];
#pragma unroll
        for (int mi = 0; mi < 4; ++mi) af[mi] = *(const bf16x8*)(As + aoff[mi]);
#pragma unroll
        for (int ni = 0; ni < 2; ++ni) bfr[ni] = *(const bf16x8*)(Bs + boff[ni]);
#pragma unroll
        for (int mi = 0; mi < 4; ++mi)
#pragma unroll
            for (int ni = 0; ni < 2; ++ni)
                acc[mi][ni] = __builtin_amdgcn_mfma_f32_16x16x32_bf16(
                    af[mi], bfr[ni], acc[mi][ni], 0, 0, 0);
        __syncthreads();
    }

    const int ccol0 = n0 + wn * 32 + (lane & 15);
    const int crow0 = m0 + wm * 64 + ((lane >> 4) << 2);
#pragma unroll
    for (int mi = 0; mi < 4; ++mi) {
#pragma unroll
        for (int ni = 0; ni < 2; ++ni) {
            const int col = ccol0 + ni * 16;
            float bsum;
            if (PACK == 3) bsum = (col < 1024) ? bias[col] : bias2[col - 1024];
            else bsum = bias[col];
#pragma unroll
            for (int r = 0; r < 4; ++r) {
                const int row = crow0 + mi * 16 + r;
                float v = acc[mi][ni][r] + bsum;
                if (ADD_PE) v += pe[((row & (S_ - 1)) << 6) + (col & (D_ - 1))];
                if (ACT) v = gelu_exact(v);
                if (PACK == 0) {
                    C[(size_t)row * E_ + col] = (__bf16)v;
                } else if (PACK == 1) {
                    C[kpack_idx(row, col)] = (__bf16)v;
                } else if (PACK == 2) {
                    C[vpack_idx(row, col)] = (__bf16)v;
                } else {
                    if (col < 1024) {
                        v += pe[((row & (S_ - 1)) << 6) + (col & (D_ - 1))];
                        C[kpack_idx(row, col)] = (__bf16)v;
                    } else {
                        C[(size_t)M_ * E_ + vpack_idx(row, col - 1024)] = (__bf16)v;
                    }
                }
            }
        }
    }
}

// ---------------------------------------------------------------------------
// Swapped-QK MFMA flash attention, LDS-staged K/V shared by 8 waves.
// Block = 8 waves x 16 q-rows = 128 q-rows. KV tile = 64 keys.
// Double-buffered LDS prefetch. XCD-chunked swizzle groups same-bh blocks.
// ---------------------------------------------------------------------------
__global__ __launch_bounds__(512) void attn_mfma(
    const __bf16* __restrict__ Q, const __bf16* __restrict__ Kp,
    const __bf16* __restrict__ Vp, __bf16* __restrict__ O) {
    __shared__ __bf16 Slds[2][2][8 * 512];  // [buf][K/V][frag*512] = 32 KB
    const int tid = threadIdx.x;
    const int lane = tid & 63;
    const int w = tid >> 6;  // 0..7
    const int l15 = lane & 15, lhi = lane >> 4;

    // XCD-chunked swizzle over grid (8, 64): XCD c owns bh in {c*8..c*8+7}
    const int id = blockIdx.y * gridDim.x + blockIdx.x;  // 0..511
    const int swz = (id & 7) * 64 + (id >> 3);
    const int q0 = (swz & 7) * 128 + w * 16;
    const int bh = swz >> 3;
    const int bb = bh >> 4, hh = bh & 15;

    // Q fragments (B-operand), pre-scaled by 1/8 (exact)
    bf16x8 qf[2];
    {
        const __bf16* qrow =
            Q + (size_t)(bb * S_ + q0 + l15) * E_ + hh * 64 + lhi * 8;
#pragma unroll
        for (int kc = 0; kc < 2; ++kc) {
            const u16x8 raw = *(const u16x8*)(qrow + kc * 32);
            bf16x8 v;
#pragma unroll
            for (int j = 0; j < 8; ++j) v[j] = (__bf16)(bf2f(raw[j]) * 0.125f);
            qf[kc] = v;
        }
    }

    // wave w stages fragment w of K and of V for tile kt into buf
    const __bf16* kpw = Kp + ((size_t)bh * 16 * 8 + w) * 512 + lane * 8;
    const __bf16* vpw = Vp + ((size_t)bh * 16 * 8 + w) * 512 + lane * 8;

    float m_l = -1e30f, l_l = 0.f;
    f32x4 oacc[4] = {};

    // prologue: stage kt=0 into buf 0
    __builtin_amdgcn_global_load_lds(
        (const __attribute__((address_space(1))) unsigned int*)(kpw),
        (__attribute__((address_space(3))) unsigned int*)(&Slds[0][0][w * 512]),
        16, 0, 0);
    __builtin_amdgcn_global_load_lds(
        (const __attribute__((address_space(1))) unsigned int*)(vpw),
        (__attribute__((address_space(3))) unsigned int*)(&Slds[0][1][w * 512]),
        16, 0, 0);

#pragma unroll 2
    for (int kt = 0; kt < S_ / 64; ++kt) {
        const int cur = kt & 1;
        __syncthreads();  // drains vmcnt: buf[cur] staging complete, all waves
        if (kt < S_ / 64 - 1) {
            const size_t fo = (size_t)(kt + 1) * 8 * 512;
            __builtin_amdgcn_global_load_lds(
                (const __attribute__((address_space(1))) unsigned int*)(kpw + fo),
                (__attribute__((address_space(3))) unsigned int*)(
                    &Slds[cur ^ 1][0][w * 512]), 16, 0, 0);
            __builtin_amdgcn_global_load_lds(
                (const __attribute__((address_space(1))) unsigned int*)(vpw + fo),
                (__attribute__((address_space(3))) unsigned int*)(
                    &Slds[cur ^ 1][1][w * 512]), 16, 0, 0);
        }
        const __bf16* kl = &Slds[cur][0][0];
        const __bf16* vl = &Slds[cur][1][0];
        // S^T = mfma(K_frag, Q_frag): col = q = l15, row = kb*16 + lhi*4 + r
        f32x4 s[4];
#pragma unroll
        for (int kb = 0; kb < 4; ++kb) {
            const bf16x8 k0 = *(const bf16x8*)(kl + (kb * 2 + 0) * 512 + lane * 8);
            const bf16x8 k1 = *(const bf16x8*)(kl + (kb * 2 + 1) * 512 + lane * 8);
            f32x4 z = {};
            z = __builtin_amdgcn_mfma_f32_16x16x32_bf16(k0, qf[0], z, 0, 0, 0);
            s[kb] = __builtin_amdgcn_mfma_f32_16x16x32_bf16(k1, qf[1], z, 0, 0, 0);
        }
        // lane-local softmax over 16 in-lane scores + 2-shfl cross-group
        float mx0 = fmaxf(fmaxf(s[0][0], s[0][1]), fmaxf(s[0][2], s[0][3]));
        float mx1 = fmaxf(fmaxf(s[1][0], s[1][1]), fmaxf(s[1][2], s[1][3]));
        float mx2 = fmaxf(fmaxf(s[2][0], s[2][1]), fmaxf(s[2][2], s[2][3]));
        float mx3 = fmaxf(fmaxf(s[3][0], s[3][1]), fmaxf(s[3][2], s[3][3]));
        float mx = fmaxf(fmaxf(mx0, mx1), fmaxf(mx2, mx3));
        mx = fmaxf(mx, __shfl_xor(mx, 16));
        mx = fmaxf(mx, __shfl_xor(mx, 32));
        const float mnew = fmaxf(m_l, mx);
        const float corr = __expf(m_l - mnew);
        float p[4][4];
        float rs = 0.f;
#pragma unroll
        for (int kb = 0; kb < 4; ++kb) {
            float sb = 0.f;
#pragma unroll
            for (int r = 0; r < 4; ++r) {
                p[kb][r] = __expf(s[kb][r] - mnew);
                sb += p[kb][r];
            }
            rs += sb;
        }
        rs += __shfl_xor(rs, 16);
        rs += __shfl_xor(rs, 32);
        l_l = l_l * corr + rs;
        m_l = mnew;
#pragma unroll
        for (int db = 0; db < 4; ++db)
#pragma unroll
            for (int r = 0; r < 4; ++r) oacc[db][r] *= corr;
        // pack P^T into B-fragments (in-lane, key-permuted to match Vp)
        bf16x8 pf[2];
#pragma unroll
        for (int kc = 0; kc < 2; ++kc) {
            bf16x8 v;
#pragma unroll
            for (int r = 0; r < 4; ++r) {
                v[r] = (__bf16)p[kc * 2][r];
                v[r + 4] = (__bf16)p[kc * 2 + 1][r];
            }
            pf[kc] = v;
        }
#pragma unroll
        for (int db = 0; db < 4; ++db) {
            const bf16x8 v0 = *(const bf16x8*)(vl + (db * 2 + 0) * 512 + lane * 8);
            const bf16x8 v1 = *(const bf16x8*)(vl + (db * 2 + 1) * 512 + lane * 8);
            oacc[db] = __builtin_amdgcn_mfma_f32_16x16x32_bf16(v0, pf[0], oacc[db], 0, 0, 0);
            oacc[db] = __builtin_amdgcn_mfma_f32_16x16x32_bf16(v1, pf[1], oacc[db], 0, 0, 0);
        }
    }
    // epilogue: O[q][d], lane holds O^T[d = db*16 + lhi*4 + r][q = l15]
    const float inv_l = 1.f / l_l;
    __bf16* orow = O + (size_t)(bb * S_ + q0 + l15) * E_ + hh * 64 + lhi * 4;
#pragma unroll
    for (int db = 0; db < 4; ++db) {
        bf16x4 ov;
#pragma unroll
        for (int r = 0; r < 4; ++r) ov[r] = (__bf16)(oacc[db][r] * inv_l);
        *(bf16x4*)(orow + db * 16) = ov;
    }
}

// ---------------------------------------------------------------------------
// out[m] = bf16 x[m,:] . f32 W_out + b_out -> f32. One wave per row.
// ---------------------------------------------------------------------------
__global__ __launch_bounds__(256) void final_proj(
    const __bf16* __restrict__ X, const float* __restrict__ Wout,
    const float* __restrict__ bout, float* __restrict__ out) {
    const int wid = threadIdx.x >> 6, lane = threadIdx.x & 63;
    const int m = blockIdx.x * 4 + wid;
    const __bf16* xrow = X + (size_t)m * E_;
    float acc = 0.f;
#pragma unroll
    for (int c = 0; c < 2; ++c) {
        const int idx = c * 512 + lane * 8;
        const u16x8 xv = *(const u16x8*)(xrow + idx);
        const float4 w1 = *(const float4*)(Wout + idx);
        const float4 w2 = *(const float4*)(Wout + idx + 4);
        acc += bf2f(xv[0]) * w1.x + bf2f(xv[1]) * w1.y + bf2f(xv[2]) * w1.z +
               bf2f(xv[3]) * w1.w + bf2f(xv[4]) * w2.x + bf2f(xv[5]) * w2.y +
               bf2f(xv[6]) * w2.z + bf2f(xv[7]) * w2.w;
    }
#pragma unroll
    for (int off = 32; off; off >>= 1) acc += __shfl_xor(acc, off, 64);
    if (lane == 0) out[m] = acc + bout[0];
}

extern "C" void kernel_launch(void* const* d_in, const int* in_sizes, int n_in,
                              void* d_out, int out_size, void* d_ws, size_t ws_size,
                              hipStream_t stream) {
    const int* item_inputs = (const int*)d_in[0];
    const int* skill_inputs = (const int*)d_in[1];
    const float* emb_item = (const float*)d_in[5];
    const float* emb_skill = (const float*)d_in[6];
    const float* W_in = (const float*)d_in[7];
    const float* b_in = (const float*)d_in[8];
    const float* Wq = (const float*)d_in[9];
    const float* bq = (const float*)d_in[10];
    const float* Wk = (const float*)d_in[11];
    const float* bk = (const float*)d_in[12];
    const float* Wv = (const float*)d_in[13];
    const float* bv = (const float*)d_in[14];
    // d_in[15] Wg, d_in[16] bg: softmax-invariant, skipped.
    const float* pos_key = (const float*)d_in[17];
    const float* Wl = (const float*)d_in[18];
    const float* bl = (const float*)d_in[19];
    const float* W_out = (const float*)d_in[20];
    const float* b_out = (const float*)d_in[21];
    float* out = (float*)d_out;

    const size_t SZ = (size_t)M_ * E_;  // 4M
    __bf16* Xc = (__bf16*)d_ws;         // 8M elems (dead after embed GEMM)
    __bf16* X = Xc + (size_t)M_ * 2048;
    __bf16* Qb = X + SZ;
    __bf16* Kp = Qb + SZ;               // packed K fragments, 4M elems
    __bf16* Vp = Kp + SZ;               // packed V fragments, 4M elems (contiguous after Kp)
    __bf16* Winb = Vp + SZ;             // 2M elems
    __bf16* Wbuf = Winb + 2 * EE;       // 6M elems

    const dim3 gg(E_ / 64, M_ / 128);   // (16, 32)
    const dim3 ggkv(2 * E_ / 64, M_ / 128);  // (32, 32) fused k|v
    const dim3 bb(256);

    embed_gather<<<dim3(M_), bb, 0, stream>>>(item_inputs, skill_inputs,
                                              emb_item, emb_skill, Xc);
    cvt_f32_bf16<<<dim3(2 * EE / 1024), bb, 0, stream>>>(W_in, Winb, 2 * EE);
    gemm_bf16<0, 0, 0><<<gg, bb, 0, stream>>>(Xc, Winb, b_in, X, 2048, nullptr, nullptr);

    for (int l = 0; l < L_; ++l) {
        cvt_layer_weights<<<dim3(6 * EE / 1024), bb, 0, stream>>>(
            Wq + (size_t)l * EE, Wk + (size_t)l * EE, Wv + (size_t)l * EE,
            Wl + (size_t)l * 3 * EE, Wbuf);
        const float* pe_l = pos_key + (size_t)l * S_ * D_;
        gemm_bf16<0, 0, 0><<<gg, bb, 0, stream>>>(X, Wbuf + 0 * EE, bq + l * E_, Qb, E_, nullptr, nullptr);
        // fused k|v: B = [Wk; Wv] (contiguous in Wbuf), writes Kp then Vp
        gemm_bf16<0, 0, 3><<<ggkv, bb, 0, stream>>>(Qb, Wbuf + 1 * EE, bk + l * E_, Kp, E_, pe_l, bv + l * E_);
        attn_mfma<<<dim3(S_ / 128, B_ * H_), dim3(512), 0, stream>>>(Qb, Kp, Vp, X);
        gemm_bf16<1, 0, 0><<<gg, bb, 0, stream>>>(X, Wbuf + 3 * EE, bl + (l * 3 + 0) * E_, Qb, E_, nullptr, nullptr);
        gemm_bf16<1, 0, 0><<<gg, bb, 0, stream>>>(Qb, Wbuf + 4 * EE, bl + (l * 3 + 1) * E_, Kp, E_, nullptr, nullptr);
        gemm_bf16<1, 0, 0><<<gg, bb, 0, stream>>>(Kp, Wbuf + 5 * EE, bl + (l * 3 + 2) * E_, X, E_, nullptr, nullptr);
    }
    final_proj<<<dim3(M_ / 4), bb, 0, stream>>>(X, W_out, b_out, out);
}

// Round 10
// 598.520 us; speedup vs baseline: 2.2245x; 1.1242x over previous
//
#include <hip/hip_runtime.h>
#include <hip/hip_bf16.h>

// AKT forward, round 10: GEMM K-loop restructured to BK=64 (16 MFMA/barrier,
// half the barriers) with full 8-quad XOR swizzle (ch ^ (row&7), both sides).
// Attn unchanged from round 9 (LDS-staged, XCD-swizzled).
//   - glo term dropped (softmax-invariant per-query constant)
//   - pos_key folded into k-GEMM epilogue
// Workspace: Xc[4096,2048]bf16 | X,Qb [4096,1024] | Kp,Vp packed 4M | W bufs

#define B_ 4
#define S_ 1024
#define E_ 1024
#define H_ 16
#define D_ 64
#define L_ 4
#define M_ (B_ * S_)  // 4096
#define EE (E_ * E_)  // 1M

typedef __attribute__((ext_vector_type(8))) __bf16 bf16x8;
typedef __attribute__((ext_vector_type(4))) __bf16 bf16x4;
typedef __attribute__((ext_vector_type(4))) float f32x4;
typedef __attribute__((ext_vector_type(8))) unsigned short u16x8;

__device__ __forceinline__ float bf2f(unsigned short u) {
    union { unsigned int i; float f; } x;
    x.i = ((unsigned int)u) << 16;
    return x.f;
}
__device__ __forceinline__ float gelu_exact(float x) {
    return 0.5f * x * (1.0f + erff(x * 0.70710678118654752f));
}

// Packed K layout: frag=((bh*16+kt)*4+kb)*2+kc, elem=lane*8+j with
//   lane = lhi*16 + l15, srow = kt*64+kb*16+l15, d = kc*32+lhi*8+j.
__device__ __forceinline__ size_t kpack_idx(int m, int col) {
    const int b = m >> 10, srow = m & (S_ - 1);
    const int h = col >> 6, d = col & 63;
    const int bh = b * H_ + h;
    const int kt = srow >> 6, kb = (srow >> 4) & 3, l15 = srow & 15;
    const int kc = d >> 5, lhi = (d >> 3) & 3, j = d & 7;
    const int frag = ((bh * 16 + kt) * 4 + kb) * 2 + kc;
    return (size_t)frag * 512 + (size_t)(lhi * 16 + l15) * 8 + j;
}
// Packed V layout (key-permuted to match P^T B-fragments).
__device__ __forceinline__ size_t vpack_idx(int m, int col) {
    const int b = m >> 10, key = m & (S_ - 1);
    const int h = col >> 6, d = col & 63;
    const int bh = b * H_ + h;
    const int kt = key >> 6;
    const int k6 = key & 63;
    const int kc = k6 >> 5, kl = k6 & 31;
    const int lhi = (kl >> 2) & 3;
    const int j = ((kl >> 4) << 2) | (kl & 3);
    const int db = d >> 4, l15 = d & 15;
    const int frag = ((bh * 16 + kt) * 4 + db) * 2 + kc;
    return (size_t)frag * 512 + (size_t)(lhi * 16 + l15) * 8 + j;
}

// ---------------------------------------------------------------------------
// f32 -> bf16 bulk convert
// ---------------------------------------------------------------------------
__global__ __launch_bounds__(256) void cvt_f32_bf16(
    const float* __restrict__ in, __bf16* __restrict__ out, int n) {
    const int i = (blockIdx.x * 256 + threadIdx.x) * 4;
    if (i >= n) return;
    const float4 v = *(const float4*)(in + i);
    __bf16* o = out + i;
    o[0] = (__bf16)v.x; o[1] = (__bf16)v.y; o[2] = (__bf16)v.z; o[3] = (__bf16)v.w;
}

// per-layer: Wq,Wk,Wv,Wl[0..2] (each 1M f32) -> Wbuf[6M] bf16
__global__ __launch_bounds__(256) void cvt_layer_weights(
    const float* __restrict__ Wq, const float* __restrict__ Wk,
    const float* __restrict__ Wv, const float* __restrict__ Wl,
    __bf16* __restrict__ out) {
    const int i = (blockIdx.x * 256 + threadIdx.x) * 4;  // < 6M
    const int mat = i >> 20;
    const int off = i & (EE - 1);
    const float* src = (mat == 0) ? Wq : (mat == 1) ? Wk : (mat == 2) ? Wv
                                        : Wl + (size_t)(mat - 3) * EE;
    const float4 v = *(const float4*)(src + off);
    __bf16* o = out + i;
    o[0] = (__bf16)v.x; o[1] = (__bf16)v.y; o[2] = (__bf16)v.z; o[3] = (__bf16)v.w;
}

// ---------------------------------------------------------------------------
// Xc[r, 0:2048] = bf16(concat(emb_item[item_idx[r]], emb_skill[skill_idx[r]]))
// ---------------------------------------------------------------------------
__global__ __launch_bounds__(256) void embed_gather(
    const int* __restrict__ item_idx, const int* __restrict__ skill_idx,
    const float* __restrict__ emb_item, const float* __restrict__ emb_skill,
    __bf16* __restrict__ Xc) {
    const int r = blockIdx.x;
    const int c = threadIdx.x * 8;
    const float* s = (c < E_) ? emb_item + (size_t)item_idx[r] * E_ + c
                              : emb_skill + (size_t)skill_idx[r] * E_ + (c - E_);
    const float4 a = *(const float4*)s;
    const float4 b = *(const float4*)(s + 4);
    __bf16* o = Xc + (size_t)r * 2048 + c;
    o[0] = (__bf16)a.x; o[1] = (__bf16)a.y; o[2] = (__bf16)a.z; o[3] = (__bf16)a.w;
    o[4] = (__bf16)b.x; o[5] = (__bf16)b.y; o[6] = (__bf16)b.z; o[7] = (__bf16)b.w;
}

// ---------------------------------------------------------------------------
// C = A[M_,K]bf16 * Bm[N,K]bf16^T + bias(f32); opt GELU / pe-add.
// PACK: 0 = row-major C; 1 = K-packed; 2 = V-packed; 3 = fused k|v (N=2048).
// BM=128, BN=64, BK=64. 256 threads = 4 waves (2x2), wave tile 64x32,
// 16 MFMA per wave per barrier-pair. Swizzle: chunk' = ch ^ (row&7), applied
// to global source (staging) and ds_read (both sides; involution).
// XCD-chunked bijective block swizzle.
// ---------------------------------------------------------------------------
template <int ACT, int ADD_PE, int PACK>
__global__ __launch_bounds__(256) void gemm_bf16(
    const __bf16* __restrict__ A, const __bf16* __restrict__ Bm,
    const float* __restrict__ bias, __bf16* __restrict__ C, int K,
    const float* __restrict__ pe, const float* __restrict__ bias2) {
    __shared__ __bf16 As[128 * 64];  // 16 KB
    __shared__ __bf16 Bs[64 * 64];   // 8 KB
    const int tid = threadIdx.x;
    const int lane = tid & 63;
    const int wid = tid >> 6;
    const int wm = wid >> 1;
    const int wn = wid & 1;
    const int l15 = lane & 15, lhi = lane >> 4;

    // XCD-chunked bijective swizzle (nwg % 8 == 0 for all grids used)
    const int gx = gridDim.x;
    const int id = blockIdx.y * gx + blockIdx.x;
    const int nwg = gx * gridDim.y;
    const int swz = (id & 7) * (nwg >> 3) + (id >> 3);
    const int m0 = (swz / gx) * 128;
    const int n0 = (swz % gx) * 64;

    // staging: A = 1024 chunks of 16B (4/thread), B = 512 chunks (2/thread).
    // chunk c -> LDS slot c (linear); source chunk = (c&7) ^ (row&7).
    const __bf16* pa[4];
    __bf16* la[4];
#pragma unroll
    for (int j = 0; j < 4; ++j) {
        const int ca = wid * 256 + j * 64 + lane;
        const int row = ca >> 3, ch = ca & 7;
        pa[j] = A + (size_t)(m0 + row) * K + ((ch ^ (row & 7)) << 3);
        la[j] = As + (size_t)ca * 8;
    }
    const __bf16* pb[2];
    __bf16* lb[2];
#pragma unroll
    for (int j = 0; j < 2; ++j) {
        const int cb = wid * 128 + j * 64 + lane;
        const int row = cb >> 3, ch = cb & 7;
        pb[j] = Bm + (size_t)(n0 + row) * K + ((ch ^ (row & 7)) << 3);
        lb[j] = Bs + (size_t)cb * 8;
    }

    // ds_read offsets (elements): row*64 + ((kc*4+lhi)^(row&7))*8
    int aoff[4][2], boff[2][2];
#pragma unroll
    for (int mi = 0; mi < 4; ++mi) {
        const int row = wm * 64 + mi * 16 + l15;
#pragma unroll
        for (int kc = 0; kc < 2; ++kc)
            aoff[mi][kc] = row * 64 + (((kc * 4 + lhi) ^ (row & 7)) << 3);
    }
#pragma unroll
    for (int ni = 0; ni < 2; ++ni) {
        const int row = wn * 32 + ni * 16 + l15;
#pragma unroll
        for (int kc = 0; kc < 2; ++kc)
            boff[ni][kc] = row * 64 + (((kc * 4 + lhi) ^ (row & 7)) << 3);
    }

    f32x4 acc[4][2] = {};

    for (int k0 = 0; k0 < K; k0 += 64) {
#pragma unroll
        for (int j = 0; j < 4; ++j)
            __builtin_amdgcn_global_load_lds(
                (const __attribute__((address_space(1))) unsigned int*)(pa[j] + k0),
                (__attribute__((address_space(3))) unsigned int*)la[j], 16, 0, 0);
#pragma unroll
        for (int j = 0; j < 2; ++j)
            __builtin_amdgcn_global_load_lds(
                (const __attribute__((address_space(1))) unsigned int*)(pb[j] + k0),
                (__attribute__((address_space(3))) unsigned int*)lb[j], 16, 0, 0);
        __syncthreads();
        bf16x8 af[4][2], bfr[2][2];
#pragma unroll
        for (int mi = 0; mi < 4; ++mi)
#pragma unroll
            for (int kc = 0; kc < 2; ++kc)
                af[mi][kc] = *(const bf16x8*)(As + aoff[mi][kc]);
#pragma unroll
        for (int ni = 0; ni < 2; ++ni)
#pragma unroll
            for (int kc = 0; kc < 2; ++kc)
                bfr[ni][kc] = *(const bf16x8*)(Bs + boff[ni][kc]);
#pragma unroll
        for (int mi = 0; mi < 4; ++mi)
#pragma unroll
            for (int ni = 0; ni < 2; ++ni)
#pragma unroll
                for (int kc = 0; kc < 2; ++kc)
                    acc[mi][ni] = __builtin_amdgcn_mfma_f32_16x16x32_bf16(
                        af[mi][kc], bfr[ni][kc], acc[mi][ni], 0, 0, 0);
        __syncthreads();
    }

    const int ccol0 = n0 + wn * 32 + l15;
    const int crow0 = m0 + wm * 64 + (lhi << 2);
#pragma unroll
    for (int mi = 0; mi < 4; ++mi) {
#pragma unroll
        for (int ni = 0; ni < 2; ++ni) {
            const int col = ccol0 + ni * 16;
            float bsum;
            if (PACK == 3) bsum = (col < 1024) ? bias[col] : bias2[col - 1024];
            else bsum = bias[col];
#pragma unroll
            for (int r = 0; r < 4; ++r) {
                const int row = crow0 + mi * 16 + r;
                float v = acc[mi][ni][r] + bsum;
                if (ADD_PE) v += pe[((row & (S_ - 1)) << 6) + (col & (D_ - 1))];
                if (ACT) v = gelu_exact(v);
                if (PACK == 0) {
                    C[(size_t)row * E_ + col] = (__bf16)v;
                } else if (PACK == 1) {
                    C[kpack_idx(row, col)] = (__bf16)v;
                } else if (PACK == 2) {
                    C[vpack_idx(row, col)] = (__bf16)v;
                } else {
                    if (col < 1024) {
                        v += pe[((row & (S_ - 1)) << 6) + (col & (D_ - 1))];
                        C[kpack_idx(row, col)] = (__bf16)v;
                    } else {
                        C[(size_t)M_ * E_ + vpack_idx(row, col - 1024)] = (__bf16)v;
                    }
                }
            }
        }
    }
}

// ---------------------------------------------------------------------------
// Swapped-QK MFMA flash attention, LDS-staged K/V shared by 8 waves.
// Block = 8 waves x 16 q-rows = 128 q-rows. KV tile = 64 keys.
// Double-buffered LDS prefetch. XCD-chunked swizzle groups same-bh blocks.
// ---------------------------------------------------------------------------
__global__ __launch_bounds__(512) void attn_mfma(
    const __bf16* __restrict__ Q, const __bf16* __restrict__ Kp,
    const __bf16* __restrict__ Vp, __bf16* __restrict__ O) {
    __shared__ __bf16 Slds[2][2][8 * 512];  // [buf][K/V][frag*512] = 32 KB
    const int tid = threadIdx.x;
    const int lane = tid & 63;
    const int w = tid >> 6;  // 0..7
    const int l15 = lane & 15, lhi = lane >> 4;

    // XCD-chunked swizzle over grid (8, 64): XCD c owns bh in {c*8..c*8+7}
    const int id = blockIdx.y * gridDim.x + blockIdx.x;  // 0..511
    const int swz = (id & 7) * 64 + (id >> 3);
    const int q0 = (swz & 7) * 128 + w * 16;
    const int bh = swz >> 3;
    const int bb = bh >> 4, hh = bh & 15;

    // Q fragments (B-operand), pre-scaled by 1/8 (exact)
    bf16x8 qf[2];
    {
        const __bf16* qrow =
            Q + (size_t)(bb * S_ + q0 + l15) * E_ + hh * 64 + lhi * 8;
#pragma unroll
        for (int kc = 0; kc < 2; ++kc) {
            const u16x8 raw = *(const u16x8*)(qrow + kc * 32);
            bf16x8 v;
#pragma unroll
            for (int j = 0; j < 8; ++j) v[j] = (__bf16)(bf2f(raw[j]) * 0.125f);
            qf[kc] = v;
        }
    }

    // wave w stages fragment w of K and of V for tile kt into buf
    const __bf16* kpw = Kp + ((size_t)bh * 16 * 8 + w) * 512 + lane * 8;
    const __bf16* vpw = Vp + ((size_t)bh * 16 * 8 + w) * 512 + lane * 8;

    float m_l = -1e30f, l_l = 0.f;
    f32x4 oacc[4] = {};

    // prologue: stage kt=0 into buf 0
    __builtin_amdgcn_global_load_lds(
        (const __attribute__((address_space(1))) unsigned int*)(kpw),
        (__attribute__((address_space(3))) unsigned int*)(&Slds[0][0][w * 512]),
        16, 0, 0);
    __builtin_amdgcn_global_load_lds(
        (const __attribute__((address_space(1))) unsigned int*)(vpw),
        (__attribute__((address_space(3))) unsigned int*)(&Slds[0][1][w * 512]),
        16, 0, 0);

#pragma unroll 2
    for (int kt = 0; kt < S_ / 64; ++kt) {
        const int cur = kt & 1;
        __syncthreads();  // drains vmcnt: buf[cur] staging complete, all waves
        if (kt < S_ / 64 - 1) {
            const size_t fo = (size_t)(kt + 1) * 8 * 512;
            __builtin_amdgcn_global_load_lds(
                (const __attribute__((address_space(1))) unsigned int*)(kpw + fo),
                (__attribute__((address_space(3))) unsigned int*)(
                    &Slds[cur ^ 1][0][w * 512]), 16, 0, 0);
            __builtin_amdgcn_global_load_lds(
                (const __attribute__((address_space(1))) unsigned int*)(vpw + fo),
                (__attribute__((address_space(3))) unsigned int*)(
                    &Slds[cur ^ 1][1][w * 512]), 16, 0, 0);
        }
        const __bf16* kl = &Slds[cur][0][0];
        const __bf16* vl = &Slds[cur][1][0];
        // S^T = mfma(K_frag, Q_frag): col = q = l15, row = kb*16 + lhi*4 + r
        f32x4 s[4];
#pragma unroll
        for (int kb = 0; kb < 4; ++kb) {
            const bf16x8 k0 = *(const bf16x8*)(kl + (kb * 2 + 0) * 512 + lane * 8);
            const bf16x8 k1 = *(const bf16x8*)(kl + (kb * 2 + 1) * 512 + lane * 8);
            f32x4 z = {};
            z = __builtin_amdgcn_mfma_f32_16x16x32_bf16(k0, qf[0], z, 0, 0, 0);
            s[kb] = __builtin_amdgcn_mfma_f32_16x16x32_bf16(k1, qf[1], z, 0, 0, 0);
        }
        // lane-local softmax over 16 in-lane scores + 2-shfl cross-group
        float mx0 = fmaxf(fmaxf(s[0][0], s[0][1]), fmaxf(s[0][2], s[0][3]));
        float mx1 = fmaxf(fmaxf(s[1][0], s[1][1]), fmaxf(s[1][2], s[1][3]));
        float mx2 = fmaxf(fmaxf(s[2][0], s[2][1]), fmaxf(s[2][2], s[2][3]));
        float mx3 = fmaxf(fmaxf(s[3][0], s[3][1]), fmaxf(s[3][2], s[3][3]));
        float mx = fmaxf(fmaxf(mx0, mx1), fmaxf(mx2, mx3));
        mx = fmaxf(mx, __shfl_xor(mx, 16));
        mx = fmaxf(mx, __shfl_xor(mx, 32));
        const float mnew = fmaxf(m_l, mx);
        const float corr = __expf(m_l - mnew);
        float p[4][4];
        float rs = 0.f;
#pragma unroll
        for (int kb = 0; kb < 4; ++kb) {
            float sb = 0.f;
#pragma unroll
            for (int r = 0; r < 4; ++r) {
                p[kb][r] = __expf(s[kb][r] - mnew);
                sb += p[kb][r];
            }
            rs += sb;
        }
        rs += __shfl_xor(rs, 16);
        rs += __shfl_xor(rs, 32);
        l_l = l_l * corr + rs;
        m_l = mnew;
#pragma unroll
        for (int db = 0; db < 4; ++db)
#pragma unroll
            for (int r = 0; r < 4; ++r) oacc[db][r] *= corr;
        // pack P^T into B-fragments (in-lane, key-permuted to match Vp)
        bf16x8 pf[2];
#pragma unroll
        for (int kc = 0; kc < 2; ++kc) {
            bf16x8 v;
#pragma unroll
            for (int r = 0; r < 4; ++r) {
                v[r] = (__bf16)p[kc * 2][r];
                v[r + 4] = (__bf16)p[kc * 2 + 1][r];
            }
            pf[kc] = v;
        }
#pragma unroll
        for (int db = 0; db < 4; ++db) {
            const bf16x8 v0 = *(const bf16x8*)(vl + (db * 2 + 0) * 512 + lane * 8);
            const bf16x8 v1 = *(const bf16x8*)(vl + (db * 2 + 1) * 512 + lane * 8);
            oacc[db] = __builtin_amdgcn_mfma_f32_16x16x32_bf16(v0, pf[0], oacc[db], 0, 0, 0);
            oacc[db] = __builtin_amdgcn_mfma_f32_16x16x32_bf16(v1, pf[1], oacc[db], 0, 0, 0);
        }
    }
    // epilogue: O[q][d], lane holds O^T[d = db*16 + lhi*4 + r][q = l15]
    const float inv_l = 1.f / l_l;
    __bf16* orow = O + (size_t)(bb * S_ + q0 + l15) * E_ + hh * 64 + lhi * 4;
#pragma unroll
    for (int db = 0; db < 4; ++db) {
        bf16x4 ov;
#pragma unroll
        for (int r = 0; r < 4; ++r) ov[r] = (__bf16)(oacc[db][r] * inv_l);
        *(bf16x4*)(orow + db * 16) = ov;
    }
}

// ---------------------------------------------------------------------------
// out[m] = bf16 x[m,:] . f32 W_out + b_out -> f32. One wave per row.
// ---------------------------------------------------------------------------
__global__ __launch_bounds__(256) void final_proj(
    const __bf16* __restrict__ X, const float* __restrict__ Wout,
    const float* __restrict__ bout, float* __restrict__ out) {
    const int wid = threadIdx.x >> 6, lane = threadIdx.x & 63;
    const int m = blockIdx.x * 4 + wid;
    const __bf16* xrow = X + (size_t)m * E_;
    float acc = 0.f;
#pragma unroll
    for (int c = 0; c < 2; ++c) {
        const int idx = c * 512 + lane * 8;
        const u16x8 xv = *(const u16x8*)(xrow + idx);
        const float4 w1 = *(const float4*)(Wout + idx);
        const float4 w2 = *(const float4*)(Wout + idx + 4);
        acc += bf2f(xv[0]) * w1.x + bf2f(xv[1]) * w1.y + bf2f(xv[2]) * w1.z +
               bf2f(xv[3]) * w1.w + bf2f(xv[4]) * w2.x + bf2f(xv[5]) * w2.y +
               bf2f(xv[6]) * w2.z + bf2f(xv[7]) * w2.w;
    }
#pragma unroll
    for (int off = 32; off; off >>= 1) acc += __shfl_xor(acc, off, 64);
    if (lane == 0) out[m] = acc + bout[0];
}

extern "C" void kernel_launch(void* const* d_in, const int* in_sizes, int n_in,
                              void* d_out, int out_size, void* d_ws, size_t ws_size,
                              hipStream_t stream) {
    const int* item_inputs = (const int*)d_in[0];
    const int* skill_inputs = (const int*)d_in[1];
    const float* emb_item = (const float*)d_in[5];
    const float* emb_skill = (const float*)d_in[6];
    const float* W_in = (const float*)d_in[7];
    const float* b_in = (const float*)d_in[8];
    const float* Wq = (const float*)d_in[9];
    const float* bq = (const float*)d_in[10];
    const float* Wk = (const float*)d_in[11];
    const float* bk = (const float*)d_in[12];
    const float* Wv = (const float*)d_in[13];
    const float* bv = (const float*)d_in[14];
    // d_in[15] Wg, d_in[16] bg: softmax-invariant, skipped.
    const float* pos_key = (const float*)d_in[17];
    const float* Wl = (const float*)d_in[18];
    const float* bl = (const float*)d_in[19];
    const float* W_out = (const float*)d_in[20];
    const float* b_out = (const float*)d_in[21];
    float* out = (float*)d_out;

    const size_t SZ = (size_t)M_ * E_;  // 4M
    __bf16* Xc = (__bf16*)d_ws;         // 8M elems (dead after embed GEMM)
    __bf16* X = Xc + (size_t)M_ * 2048;
    __bf16* Qb = X + SZ;
    __bf16* Kp = Qb + SZ;               // packed K fragments, 4M elems
    __bf16* Vp = Kp + SZ;               // packed V fragments, 4M elems (contiguous after Kp)
    __bf16* Winb = Vp + SZ;             // 2M elems
    __bf16* Wbuf = Winb + 2 * EE;       // 6M elems

    const dim3 gg(E_ / 64, M_ / 128);   // (16, 32)
    const dim3 ggkv(2 * E_ / 64, M_ / 128);  // (32, 32) fused k|v
    const dim3 bb(256);

    embed_gather<<<dim3(M_), bb, 0, stream>>>(item_inputs, skill_inputs,
                                              emb_item, emb_skill, Xc);
    cvt_f32_bf16<<<dim3(2 * EE / 1024), bb, 0, stream>>>(W_in, Winb, 2 * EE);
    gemm_bf16<0, 0, 0><<<gg, bb, 0, stream>>>(Xc, Winb, b_in, X, 2048, nullptr, nullptr);

    for (int l = 0; l < L_; ++l) {
        cvt_layer_weights<<<dim3(6 * EE / 1024), bb, 0, stream>>>(
            Wq + (size_t)l * EE, Wk + (size_t)l * EE, Wv + (size_t)l * EE,
            Wl + (size_t)l * 3 * EE, Wbuf);
        const float* pe_l = pos_key + (size_t)l * S_ * D_;
        gemm_bf16<0, 0, 0><<<gg, bb, 0, stream>>>(X, Wbuf + 0 * EE, bq + l * E_, Qb, E_, nullptr, nullptr);
        // fused k|v: B = [Wk; Wv] (contiguous in Wbuf), writes Kp then Vp
        gemm_bf16<0, 0, 3><<<ggkv, bb, 0, stream>>>(Qb, Wbuf + 1 * EE, bk + l * E_, Kp, E_, pe_l, bv + l * E_);
        attn_mfma<<<dim3(S_ / 128, B_ * H_), dim3(512), 0, stream>>>(Qb, Kp, Vp, X);
        gemm_bf16<1, 0, 0><<<gg, bb, 0, stream>>>(X, Wbuf + 3 * EE, bl + (l * 3 + 0) * E_, Qb, E_, nullptr, nullptr);
        gemm_bf16<1, 0, 0><<<gg, bb, 0, stream>>>(Qb, Wbuf + 4 * EE, bl + (l * 3 + 1) * E_, Kp, E_, nullptr, nullptr);
        gemm_bf16<1, 0, 0><<<gg, bb, 0, stream>>>(Kp, Wbuf + 5 * EE, bl + (l * 3 + 2) * E_, X, E_, nullptr, nullptr);
    }
    final_proj<<<dim3(M_ / 4), bb, 0, stream>>>(X, W_out, b_out, out);
}

// Round 11
// 596.413 us; speedup vs baseline: 2.2323x; 1.0035x over previous
//
#include <hip/hip_runtime.h>
#include <hip/hip_bf16.h>

// AKT forward, round 11: GEMM K-loop -> T3 2-phase double-buffered pipeline
// (stage(t+1) issued after barrier, overlaps compute(t); ONE barrier/step).
// All-layer weight cvt hoisted to a single upfront kernel.
//   - glo term dropped (softmax-invariant per-query constant)
//   - pos_key folded into k-GEMM epilogue
// Workspace (~100 MB): Xc 8M | X,Qb,Kp,Vp 4M each | Winb 2M | Wall 24M elems

#define B_ 4
#define S_ 1024
#define E_ 1024
#define H_ 16
#define D_ 64
#define L_ 4
#define M_ (B_ * S_)  // 4096
#define EE (E_ * E_)  // 1M

typedef __attribute__((ext_vector_type(8))) __bf16 bf16x8;
typedef __attribute__((ext_vector_type(4))) __bf16 bf16x4;
typedef __attribute__((ext_vector_type(4))) float f32x4;
typedef __attribute__((ext_vector_type(8))) unsigned short u16x8;

__device__ __forceinline__ float bf2f(unsigned short u) {
    union { unsigned int i; float f; } x;
    x.i = ((unsigned int)u) << 16;
    return x.f;
}
__device__ __forceinline__ float gelu_exact(float x) {
    return 0.5f * x * (1.0f + erff(x * 0.70710678118654752f));
}

// Packed K layout: frag=((bh*16+kt)*4+kb)*2+kc, elem=lane*8+j with
//   lane = lhi*16 + l15, srow = kt*64+kb*16+l15, d = kc*32+lhi*8+j.
__device__ __forceinline__ size_t kpack_idx(int m, int col) {
    const int b = m >> 10, srow = m & (S_ - 1);
    const int h = col >> 6, d = col & 63;
    const int bh = b * H_ + h;
    const int kt = srow >> 6, kb = (srow >> 4) & 3, l15 = srow & 15;
    const int kc = d >> 5, lhi = (d >> 3) & 3, j = d & 7;
    const int frag = ((bh * 16 + kt) * 4 + kb) * 2 + kc;
    return (size_t)frag * 512 + (size_t)(lhi * 16 + l15) * 8 + j;
}
// Packed V layout (key-permuted to match P^T B-fragments).
__device__ __forceinline__ size_t vpack_idx(int m, int col) {
    const int b = m >> 10, key = m & (S_ - 1);
    const int h = col >> 6, d = col & 63;
    const int bh = b * H_ + h;
    const int kt = key >> 6;
    const int k6 = key & 63;
    const int kc = k6 >> 5, kl = k6 & 31;
    const int lhi = (kl >> 2) & 3;
    const int j = ((kl >> 4) << 2) | (kl & 3);
    const int db = d >> 4, l15 = d & 15;
    const int frag = ((bh * 16 + kt) * 4 + db) * 2 + kc;
    return (size_t)frag * 512 + (size_t)(lhi * 16 + l15) * 8 + j;
}

// ---------------------------------------------------------------------------
// f32 -> bf16 bulk convert (W_in)
// ---------------------------------------------------------------------------
__global__ __launch_bounds__(256) void cvt_f32_bf16(
    const float* __restrict__ in, __bf16* __restrict__ out, int n) {
    const int i = (blockIdx.x * 256 + threadIdx.x) * 4;
    if (i >= n) return;
    const float4 v = *(const float4*)(in + i);
    __bf16* o = out + i;
    o[0] = (__bf16)v.x; o[1] = (__bf16)v.y; o[2] = (__bf16)v.z; o[3] = (__bf16)v.w;
}

// ALL layers: Wq,Wk,Wv,Wl (L_ layers, 6 matrices each) -> Wall[24M] bf16
__global__ __launch_bounds__(256) void cvt_all_weights(
    const float* __restrict__ Wq, const float* __restrict__ Wk,
    const float* __restrict__ Wv, const float* __restrict__ Wl,
    __bf16* __restrict__ out) {
    const int i = (blockIdx.x * 256 + threadIdx.x) * 4;  // < 24M
    const int l = i / (6 * EE);
    const int r = i - l * 6 * EE;
    const int mat = r >> 20;
    const int off = r & (EE - 1);
    const float* src = (mat == 0) ? Wq + (size_t)l * EE
                     : (mat == 1) ? Wk + (size_t)l * EE
                     : (mat == 2) ? Wv + (size_t)l * EE
                                  : Wl + ((size_t)l * 3 + (mat - 3)) * EE;
    const float4 v = *(const float4*)(src + off);
    __bf16* o = out + i;
    o[0] = (__bf16)v.x; o[1] = (__bf16)v.y; o[2] = (__bf16)v.z; o[3] = (__bf16)v.w;
}

// ---------------------------------------------------------------------------
// Xc[r, 0:2048] = bf16(concat(emb_item[item_idx[r]], emb_skill[skill_idx[r]]))
// ---------------------------------------------------------------------------
__global__ __launch_bounds__(256) void embed_gather(
    const int* __restrict__ item_idx, const int* __restrict__ skill_idx,
    const float* __restrict__ emb_item, const float* __restrict__ emb_skill,
    __bf16* __restrict__ Xc) {
    const int r = blockIdx.x;
    const int c = threadIdx.x * 8;
    const float* s = (c < E_) ? emb_item + (size_t)item_idx[r] * E_ + c
                              : emb_skill + (size_t)skill_idx[r] * E_ + (c - E_);
    const float4 a = *(const float4*)s;
    const float4 b = *(const float4*)(s + 4);
    __bf16* o = Xc + (size_t)r * 2048 + c;
    o[0] = (__bf16)a.x; o[1] = (__bf16)a.y; o[2] = (__bf16)a.z; o[3] = (__bf16)a.w;
    o[4] = (__bf16)b.x; o[5] = (__bf16)b.y; o[6] = (__bf16)b.z; o[7] = (__bf16)b.w;
}

// ---------------------------------------------------------------------------
// C = A[M_,K]bf16 * Bm[N,K]bf16^T + bias(f32); opt GELU / pe-add.
// PACK: 0 = row-major C; 1 = K-packed; 2 = V-packed; 3 = fused k|v (N=2048).
// BM=128, BN=64, BK=64; 4 waves, 16 MFMA/wave/step.
// T3 2-phase: double-buffered LDS, stage(t+1) issued after the barrier so it
// overlaps compute(t); ONE __syncthreads per K-step.
// Swizzle chunk' = ch ^ (row&7) on both sides. XCD-chunked block swizzle.
// ---------------------------------------------------------------------------
template <int ACT, int ADD_PE, int PACK>
__global__ __launch_bounds__(256) void gemm_bf16(
    const __bf16* __restrict__ A, const __bf16* __restrict__ Bm,
    const float* __restrict__ bias, __bf16* __restrict__ C, int K,
    const float* __restrict__ pe, const float* __restrict__ bias2) {
    __shared__ __bf16 As[2][128 * 64];  // 32 KB
    __shared__ __bf16 Bs[2][64 * 64];   // 16 KB
    const int tid = threadIdx.x;
    const int lane = tid & 63;
    const int wid = tid >> 6;
    const int wm = wid >> 1;
    const int wn = wid & 1;
    const int l15 = lane & 15, lhi = lane >> 4;

    // XCD-chunked bijective swizzle (nwg % 8 == 0 for all grids used)
    const int gx = gridDim.x;
    const int id = blockIdx.y * gx + blockIdx.x;
    const int nwg = gx * gridDim.y;
    const int swz = (id & 7) * (nwg >> 3) + (id >> 3);
    const int m0 = (swz / gx) * 128;
    const int n0 = (swz % gx) * 64;

    // staging: A = 1024 chunks of 16B (4/thread), B = 512 chunks (2/thread).
    // chunk c -> LDS slot c (linear); source chunk = (c&7) ^ (row&7).
    const __bf16* pa[4];
    int laoff[4];
#pragma unroll
    for (int j = 0; j < 4; ++j) {
        const int ca = wid * 256 + j * 64 + lane;
        const int row = ca >> 3, ch = ca & 7;
        pa[j] = A + (size_t)(m0 + row) * K + ((ch ^ (row & 7)) << 3);
        laoff[j] = ca * 8;
    }
    const __bf16* pb[2];
    int lboff[2];
#pragma unroll
    for (int j = 0; j < 2; ++j) {
        const int cb = wid * 128 + j * 64 + lane;
        const int row = cb >> 3, ch = cb & 7;
        pb[j] = Bm + (size_t)(n0 + row) * K + ((ch ^ (row & 7)) << 3);
        lboff[j] = cb * 8;
    }

    // ds_read offsets (elements): row*64 + ((kc*4+lhi)^(row&7))*8
    int aoff[4][2], boff[2][2];
#pragma unroll
    for (int mi = 0; mi < 4; ++mi) {
        const int row = wm * 64 + mi * 16 + l15;
#pragma unroll
        for (int kc = 0; kc < 2; ++kc)
            aoff[mi][kc] = row * 64 + (((kc * 4 + lhi) ^ (row & 7)) << 3);
    }
#pragma unroll
    for (int ni = 0; ni < 2; ++ni) {
        const int row = wn * 32 + ni * 16 + l15;
#pragma unroll
        for (int kc = 0; kc < 2; ++kc)
            boff[ni][kc] = row * 64 + (((kc * 4 + lhi) ^ (row & 7)) << 3);
    }

    f32x4 acc[4][2] = {};
    const int NT = K >> 6;

    // prologue: stage t=0 into buf 0
#pragma unroll
    for (int j = 0; j < 4; ++j)
        __builtin_amdgcn_global_load_lds(
            (const __attribute__((address_space(1))) unsigned int*)(pa[j]),
            (__attribute__((address_space(3))) unsigned int*)(&As[0][0] + laoff[j]),
            16, 0, 0);
#pragma unroll
    for (int j = 0; j < 2; ++j)
        __builtin_amdgcn_global_load_lds(
            (const __attribute__((address_space(1))) unsigned int*)(pb[j]),
            (__attribute__((address_space(3))) unsigned int*)(&Bs[0][0] + lboff[j]),
            16, 0, 0);

    for (int t = 0; t < NT; ++t) {
        const int cur = t & 1;
        __syncthreads();  // drains vmcnt: buf[cur] ready; buf[cur^1] free
        if (t + 1 < NT) {
            const size_t koff = (size_t)(t + 1) << 6;
#pragma unroll
            for (int j = 0; j < 4; ++j)
                __builtin_amdgcn_global_load_lds(
                    (const __attribute__((address_space(1))) unsigned int*)(pa[j] + koff),
                    (__attribute__((address_space(3))) unsigned int*)(
                        &As[cur ^ 1][0] + laoff[j]), 16, 0, 0);
#pragma unroll
            for (int j = 0; j < 2; ++j)
                __builtin_amdgcn_global_load_lds(
                    (const __attribute__((address_space(1))) unsigned int*)(pb[j] + koff),
                    (__attribute__((address_space(3))) unsigned int*)(
                        &Bs[cur ^ 1][0] + lboff[j]), 16, 0, 0);
        }
        bf16x8 af[4][2], bfr[2][2];
#pragma unroll
        for (int mi = 0; mi < 4; ++mi)
#pragma unroll
            for (int kc = 0; kc < 2; ++kc)
                af[mi][kc] = *(const bf16x8*)(&As[cur][0] + aoff[mi][kc]);
#pragma unroll
        for (int ni = 0; ni < 2; ++ni)
#pragma unroll
            for (int kc = 0; kc < 2; ++kc)
                bfr[ni][kc] = *(const bf16x8*)(&Bs[cur][0] + boff[ni][kc]);
#pragma unroll
        for (int mi = 0; mi < 4; ++mi)
#pragma unroll
            for (int ni = 0; ni < 2; ++ni)
#pragma unroll
                for (int kc = 0; kc < 2; ++kc)
                    acc[mi][ni] = __builtin_amdgcn_mfma_f32_16x16x32_bf16(
                        af[mi][kc], bfr[ni][kc], acc[mi][ni], 0, 0, 0);
    }

    const int ccol0 = n0 + wn * 32 + l15;
    const int crow0 = m0 + wm * 64 + (lhi << 2);
#pragma unroll
    for (int mi = 0; mi < 4; ++mi) {
#pragma unroll
        for (int ni = 0; ni < 2; ++ni) {
            const int col = ccol0 + ni * 16;
            float bsum;
            if (PACK == 3) bsum = (col < 1024) ? bias[col] : bias2[col - 1024];
            else bsum = bias[col];
#pragma unroll
            for (int r = 0; r < 4; ++r) {
                const int row = crow0 + mi * 16 + r;
                float v = acc[mi][ni][r] + bsum;
                if (ADD_PE) v += pe[((row & (S_ - 1)) << 6) + (col & (D_ - 1))];
                if (ACT) v = gelu_exact(v);
                if (PACK == 0) {
                    C[(size_t)row * E_ + col] = (__bf16)v;
                } else if (PACK == 1) {
                    C[kpack_idx(row, col)] = (__bf16)v;
                } else if (PACK == 2) {
                    C[vpack_idx(row, col)] = (__bf16)v;
                } else {
                    if (col < 1024) {
                        v += pe[((row & (S_ - 1)) << 6) + (col & (D_ - 1))];
                        C[kpack_idx(row, col)] = (__bf16)v;
                    } else {
                        C[(size_t)M_ * E_ + vpack_idx(row, col - 1024)] = (__bf16)v;
                    }
                }
            }
        }
    }
}

// ---------------------------------------------------------------------------
// Swapped-QK MFMA flash attention, LDS-staged K/V shared by 8 waves.
// Block = 8 waves x 16 q-rows = 128 q-rows. KV tile = 64 keys.
// Double-buffered LDS prefetch. XCD-chunked swizzle groups same-bh blocks.
// ---------------------------------------------------------------------------
__global__ __launch_bounds__(512) void attn_mfma(
    const __bf16* __restrict__ Q, const __bf16* __restrict__ Kp,
    const __bf16* __restrict__ Vp, __bf16* __restrict__ O) {
    __shared__ __bf16 Slds[2][2][8 * 512];  // [buf][K/V][frag*512] = 32 KB
    const int tid = threadIdx.x;
    const int lane = tid & 63;
    const int w = tid >> 6;  // 0..7
    const int l15 = lane & 15, lhi = lane >> 4;

    // XCD-chunked swizzle over grid (8, 64): XCD c owns bh in {c*8..c*8+7}
    const int id = blockIdx.y * gridDim.x + blockIdx.x;  // 0..511
    const int swz = (id & 7) * 64 + (id >> 3);
    const int q0 = (swz & 7) * 128 + w * 16;
    const int bh = swz >> 3;
    const int bb = bh >> 4, hh = bh & 15;

    // Q fragments (B-operand), pre-scaled by 1/8 (exact)
    bf16x8 qf[2];
    {
        const __bf16* qrow =
            Q + (size_t)(bb * S_ + q0 + l15) * E_ + hh * 64 + lhi * 8;
#pragma unroll
        for (int kc = 0; kc < 2; ++kc) {
            const u16x8 raw = *(const u16x8*)(qrow + kc * 32);
            bf16x8 v;
#pragma unroll
            for (int j = 0; j < 8; ++j) v[j] = (__bf16)(bf2f(raw[j]) * 0.125f);
            qf[kc] = v;
        }
    }

    // wave w stages fragment w of K and of V for tile kt into buf
    const __bf16* kpw = Kp + ((size_t)bh * 16 * 8 + w) * 512 + lane * 8;
    const __bf16* vpw = Vp + ((size_t)bh * 16 * 8 + w) * 512 + lane * 8;

    float m_l = -1e30f, l_l = 0.f;
    f32x4 oacc[4] = {};

    // prologue: stage kt=0 into buf 0
    __builtin_amdgcn_global_load_lds(
        (const __attribute__((address_space(1))) unsigned int*)(kpw),
        (__attribute__((address_space(3))) unsigned int*)(&Slds[0][0][w * 512]),
        16, 0, 0);
    __builtin_amdgcn_global_load_lds(
        (const __attribute__((address_space(1))) unsigned int*)(vpw),
        (__attribute__((address_space(3))) unsigned int*)(&Slds[0][1][w * 512]),
        16, 0, 0);

#pragma unroll 2
    for (int kt = 0; kt < S_ / 64; ++kt) {
        const int cur = kt & 1;
        __syncthreads();  // drains vmcnt: buf[cur] staging complete, all waves
        if (kt < S_ / 64 - 1) {
            const size_t fo = (size_t)(kt + 1) * 8 * 512;
            __builtin_amdgcn_global_load_lds(
                (const __attribute__((address_space(1))) unsigned int*)(kpw + fo),
                (__attribute__((address_space(3))) unsigned int*)(
                    &Slds[cur ^ 1][0][w * 512]), 16, 0, 0);
            __builtin_amdgcn_global_load_lds(
                (const __attribute__((address_space(1))) unsigned int*)(vpw + fo),
                (__attribute__((address_space(3))) unsigned int*)(
                    &Slds[cur ^ 1][1][w * 512]), 16, 0, 0);
        }
        const __bf16* kl = &Slds[cur][0][0];
        const __bf16* vl = &Slds[cur][1][0];
        // S^T = mfma(K_frag, Q_frag): col = q = l15, row = kb*16 + lhi*4 + r
        f32x4 s[4];
#pragma unroll
        for (int kb = 0; kb < 4; ++kb) {
            const bf16x8 k0 = *(const bf16x8*)(kl + (kb * 2 + 0) * 512 + lane * 8);
            const bf16x8 k1 = *(const bf16x8*)(kl + (kb * 2 + 1) * 512 + lane * 8);
            f32x4 z = {};
            z = __builtin_amdgcn_mfma_f32_16x16x32_bf16(k0, qf[0], z, 0, 0, 0);
            s[kb] = __builtin_amdgcn_mfma_f32_16x16x32_bf16(k1, qf[1], z, 0, 0, 0);
        }
        // lane-local softmax over 16 in-lane scores + 2-shfl cross-group
        float mx0 = fmaxf(fmaxf(s[0][0], s[0][1]), fmaxf(s[0][2], s[0][3]));
        float mx1 = fmaxf(fmaxf(s[1][0], s[1][1]), fmaxf(s[1][2], s[1][3]));
        float mx2 = fmaxf(fmaxf(s[2][0], s[2][1]), fmaxf(s[2][2], s[2][3]));
        float mx3 = fmaxf(fmaxf(s[3][0], s[3][1]), fmaxf(s[3][2], s[3][3]));
        float mx = fmaxf(fmaxf(mx0, mx1), fmaxf(mx2, mx3));
        mx = fmaxf(mx, __shfl_xor(mx, 16));
        mx = fmaxf(mx, __shfl_xor(mx, 32));
        const float mnew = fmaxf(m_l, mx);
        const float corr = __expf(m_l - mnew);
        float p[4][4];
        float rs = 0.f;
#pragma unroll
        for (int kb = 0; kb < 4; ++kb) {
            float sb = 0.f;
#pragma unroll
            for (int r = 0; r < 4; ++r) {
                p[kb][r] = __expf(s[kb][r] - mnew);
                sb += p[kb][r];
            }
            rs += sb;
        }
        rs += __shfl_xor(rs, 16);
        rs += __shfl_xor(rs, 32);
        l_l = l_l * corr + rs;
        m_l = mnew;
#pragma unroll
        for (int db = 0; db < 4; ++db)
#pragma unroll
            for (int r = 0; r < 4; ++r) oacc[db][r] *= corr;
        // pack P^T into B-fragments (in-lane, key-permuted to match Vp)
        bf16x8 pf[2];
#pragma unroll
        for (int kc = 0; kc < 2; ++kc) {
            bf16x8 v;
#pragma unroll
            for (int r = 0; r < 4; ++r) {
                v[r] = (__bf16)p[kc * 2][r];
                v[r + 4] = (__bf16)p[kc * 2 + 1][r];
            }
            pf[kc] = v;
        }
#pragma unroll
        for (int db = 0; db < 4; ++db) {
            const bf16x8 v0 = *(const bf16x8*)(vl + (db * 2 + 0) * 512 + lane * 8);
            const bf16x8 v1 = *(const bf16x8*)(vl + (db * 2 + 1) * 512 + lane * 8);
            oacc[db] = __builtin_amdgcn_mfma_f32_16x16x32_bf16(v0, pf[0], oacc[db], 0, 0, 0);
            oacc[db] = __builtin_amdgcn_mfma_f32_16x16x32_bf16(v1, pf[1], oacc[db], 0, 0, 0);
        }
    }
    // epilogue: O[q][d], lane holds O^T[d = db*16 + lhi*4 + r][q = l15]
    const float inv_l = 1.f / l_l;
    __bf16* orow = O + (size_t)(bb * S_ + q0 + l15) * E_ + hh * 64 + lhi * 4;
#pragma unroll
    for (int db = 0; db < 4; ++db) {
        bf16x4 ov;
#pragma unroll
        for (int r = 0; r < 4; ++r) ov[r] = (__bf16)(oacc[db][r] * inv_l);
        *(bf16x4*)(orow + db * 16) = ov;
    }
}

// ---------------------------------------------------------------------------
// out[m] = bf16 x[m,:] . f32 W_out + b_out -> f32. One wave per row.
// ---------------------------------------------------------------------------
__global__ __launch_bounds__(256) void final_proj(
    const __bf16* __restrict__ X, const float* __restrict__ Wout,
    const float* __restrict__ bout, float* __restrict__ out) {
    const int wid = threadIdx.x >> 6, lane = threadIdx.x & 63;
    const int m = blockIdx.x * 4 + wid;
    const __bf16* xrow = X + (size_t)m * E_;
    float acc = 0.f;
#pragma unroll
    for (int c = 0; c < 2; ++c) {
        const int idx = c * 512 + lane * 8;
        const u16x8 xv = *(const u16x8*)(xrow + idx);
        const float4 w1 = *(const float4*)(Wout + idx);
        const float4 w2 = *(const float4*)(Wout + idx + 4);
        acc += bf2f(xv[0]) * w1.x + bf2f(xv[1]) * w1.y + bf2f(xv[2]) * w1.z +
               bf2f(xv[3]) * w1.w + bf2f(xv[4]) * w2.x + bf2f(xv[5]) * w2.y +
               bf2f(xv[6]) * w2.z + bf2f(xv[7]) * w2.w;
    }
#pragma unroll
    for (int off = 32; off; off >>= 1) acc += __shfl_xor(acc, off, 64);
    if (lane == 0) out[m] = acc + bout[0];
}

extern "C" void kernel_launch(void* const* d_in, const int* in_sizes, int n_in,
                              void* d_out, int out_size, void* d_ws, size_t ws_size,
                              hipStream_t stream) {
    const int* item_inputs = (const int*)d_in[0];
    const int* skill_inputs = (const int*)d_in[1];
    const float* emb_item = (const float*)d_in[5];
    const float* emb_skill = (const float*)d_in[6];
    const float* W_in = (const float*)d_in[7];
    const float* b_in = (const float*)d_in[8];
    const float* Wq = (const float*)d_in[9];
    const float* bq = (const float*)d_in[10];
    const float* Wk = (const float*)d_in[11];
    const float* bk = (const float*)d_in[12];
    const float* Wv = (const float*)d_in[13];
    const float* bv = (const float*)d_in[14];
    // d_in[15] Wg, d_in[16] bg: softmax-invariant, skipped.
    const float* pos_key = (const float*)d_in[17];
    const float* Wl = (const float*)d_in[18];
    const float* bl = (const float*)d_in[19];
    const float* W_out = (const float*)d_in[20];
    const float* b_out = (const float*)d_in[21];
    float* out = (float*)d_out;

    const size_t SZ = (size_t)M_ * E_;  // 4M
    __bf16* Xc = (__bf16*)d_ws;         // 8M elems (dead after embed GEMM)
    __bf16* X = Xc + (size_t)M_ * 2048;
    __bf16* Qb = X + SZ;
    __bf16* Kp = Qb + SZ;               // packed K fragments, 4M elems
    __bf16* Vp = Kp + SZ;               // packed V fragments, 4M (contiguous after Kp)
    __bf16* Winb = Vp + SZ;             // 2M elems
    __bf16* Wall = Winb + 2 * EE;       // 24M elems (all layers)

    const dim3 gg(E_ / 64, M_ / 128);   // (16, 32)
    const dim3 ggkv(2 * E_ / 64, M_ / 128);  // (32, 32) fused k|v
    const dim3 bb(256);

    embed_gather<<<dim3(M_), bb, 0, stream>>>(item_inputs, skill_inputs,
                                              emb_item, emb_skill, Xc);
    cvt_f32_bf16<<<dim3(2 * EE / 1024), bb, 0, stream>>>(W_in, Winb, 2 * EE);
    cvt_all_weights<<<dim3(L_ * 6 * EE / 1024), bb, 0, stream>>>(Wq, Wk, Wv, Wl, Wall);
    gemm_bf16<0, 0, 0><<<gg, bb, 0, stream>>>(Xc, Winb, b_in, X, 2048, nullptr, nullptr);

    for (int l = 0; l < L_; ++l) {
        __bf16* Wbuf = Wall + (size_t)l * 6 * EE;
        const float* pe_l = pos_key + (size_t)l * S_ * D_;
        gemm_bf16<0, 0, 0><<<gg, bb, 0, stream>>>(X, Wbuf + 0 * EE, bq + l * E_, Qb, E_, nullptr, nullptr);
        // fused k|v: B = [Wk; Wv] (contiguous in Wbuf), writes Kp then Vp
        gemm_bf16<0, 0, 3><<<ggkv, bb, 0, stream>>>(Qb, Wbuf + 1 * EE, bk + l * E_, Kp, E_, pe_l, bv + l * E_);
        attn_mfma<<<dim3(S_ / 128, B_ * H_), dim3(512), 0, stream>>>(Qb, Kp, Vp, X);
        gemm_bf16<1, 0, 0><<<gg, bb, 0, stream>>>(X, Wbuf + 3 * EE, bl + (l * 3 + 0) * E_, Qb, E_, nullptr, nullptr);
        gemm_bf16<1, 0, 0><<<gg, bb, 0, stream>>>(Qb, Wbuf + 4 * EE, bl + (l * 3 + 1) * E_, Kp, E_, nullptr, nullptr);
        gemm_bf16<1, 0, 0><<<gg, bb, 0, stream>>>(Kp, Wbuf + 5 * EE, bl + (l * 3 + 2) * E_, X, E_, nullptr, nullptr);
    }
    final_proj<<<dim3(M_ / 4), bb, 0, stream>>>(X, W_out, b_out, out);
}

// Round 12
// 585.985 us; speedup vs baseline: 2.2720x; 1.0178x over previous
//
#include <hip/hip_runtime.h>
#include <hip/hip_bf16.h>

// AKT forward, round 12: GEMM K-loop -> 3-deep counted-vmcnt pipeline (T4):
// s_waitcnt vmcnt(12) (never 0 in steady state) + raw barriers; stage lands
// ~2 compute-phases after issue. Attn unchanged.
//   - glo term dropped (softmax-invariant per-query constant)
//   - pos_key folded into k-GEMM epilogue
// Workspace (~100 MB): Xc 8M | X,Qb,Kp,Vp 4M each | Winb 2M | Wall 24M elems

#define B_ 4
#define S_ 1024
#define E_ 1024
#define H_ 16
#define D_ 64
#define L_ 4
#define M_ (B_ * S_)  // 4096
#define EE (E_ * E_)  // 1M

typedef __attribute__((ext_vector_type(8))) __bf16 bf16x8;
typedef __attribute__((ext_vector_type(4))) __bf16 bf16x4;
typedef __attribute__((ext_vector_type(4))) float f32x4;
typedef __attribute__((ext_vector_type(8))) unsigned short u16x8;

__device__ __forceinline__ float bf2f(unsigned short u) {
    union { unsigned int i; float f; } x;
    x.i = ((unsigned int)u) << 16;
    return x.f;
}
__device__ __forceinline__ float gelu_exact(float x) {
    return 0.5f * x * (1.0f + erff(x * 0.70710678118654752f));
}

// Packed K layout: frag=((bh*16+kt)*4+kb)*2+kc, elem=lane*8+j with
//   lane = lhi*16 + l15, srow = kt*64+kb*16+l15, d = kc*32+lhi*8+j.
__device__ __forceinline__ size_t kpack_idx(int m, int col) {
    const int b = m >> 10, srow = m & (S_ - 1);
    const int h = col >> 6, d = col & 63;
    const int bh = b * H_ + h;
    const int kt = srow >> 6, kb = (srow >> 4) & 3, l15 = srow & 15;
    const int kc = d >> 5, lhi = (d >> 3) & 3, j = d & 7;
    const int frag = ((bh * 16 + kt) * 4 + kb) * 2 + kc;
    return (size_t)frag * 512 + (size_t)(lhi * 16 + l15) * 8 + j;
}
// Packed V layout (key-permuted to match P^T B-fragments).
__device__ __forceinline__ size_t vpack_idx(int m, int col) {
    const int b = m >> 10, key = m & (S_ - 1);
    const int h = col >> 6, d = col & 63;
    const int bh = b * H_ + h;
    const int kt = key >> 6;
    const int k6 = key & 63;
    const int kc = k6 >> 5, kl = k6 & 31;
    const int lhi = (kl >> 2) & 3;
    const int j = ((kl >> 4) << 2) | (kl & 3);
    const int db = d >> 4, l15 = d & 15;
    const int frag = ((bh * 16 + kt) * 4 + db) * 2 + kc;
    return (size_t)frag * 512 + (size_t)(lhi * 16 + l15) * 8 + j;
}

// ---------------------------------------------------------------------------
// f32 -> bf16 bulk convert (W_in)
// ---------------------------------------------------------------------------
__global__ __launch_bounds__(256) void cvt_f32_bf16(
    const float* __restrict__ in, __bf16* __restrict__ out, int n) {
    const int i = (blockIdx.x * 256 + threadIdx.x) * 4;
    if (i >= n) return;
    const float4 v = *(const float4*)(in + i);
    __bf16* o = out + i;
    o[0] = (__bf16)v.x; o[1] = (__bf16)v.y; o[2] = (__bf16)v.z; o[3] = (__bf16)v.w;
}

// ALL layers: Wq,Wk,Wv,Wl (L_ layers, 6 matrices each) -> Wall[24M] bf16
__global__ __launch_bounds__(256) void cvt_all_weights(
    const float* __restrict__ Wq, const float* __restrict__ Wk,
    const float* __restrict__ Wv, const float* __restrict__ Wl,
    __bf16* __restrict__ out) {
    const int i = (blockIdx.x * 256 + threadIdx.x) * 4;  // < 24M
    const int l = i / (6 * EE);
    const int r = i - l * 6 * EE;
    const int mat = r >> 20;
    const int off = r & (EE - 1);
    const float* src = (mat == 0) ? Wq + (size_t)l * EE
                     : (mat == 1) ? Wk + (size_t)l * EE
                     : (mat == 2) ? Wv + (size_t)l * EE
                                  : Wl + ((size_t)l * 3 + (mat - 3)) * EE;
    const float4 v = *(const float4*)(src + off);
    __bf16* o = out + i;
    o[0] = (__bf16)v.x; o[1] = (__bf16)v.y; o[2] = (__bf16)v.z; o[3] = (__bf16)v.w;
}

// ---------------------------------------------------------------------------
// Xc[r, 0:2048] = bf16(concat(emb_item[item_idx[r]], emb_skill[skill_idx[r]]))
// ---------------------------------------------------------------------------
__global__ __launch_bounds__(256) void embed_gather(
    const int* __restrict__ item_idx, const int* __restrict__ skill_idx,
    const float* __restrict__ emb_item, const float* __restrict__ emb_skill,
    __bf16* __restrict__ Xc) {
    const int r = blockIdx.x;
    const int c = threadIdx.x * 8;
    const float* s = (c < E_) ? emb_item + (size_t)item_idx[r] * E_ + c
                              : emb_skill + (size_t)skill_idx[r] * E_ + (c - E_);
    const float4 a = *(const float4*)s;
    const float4 b = *(const float4*)(s + 4);
    __bf16* o = Xc + (size_t)r * 2048 + c;
    o[0] = (__bf16)a.x; o[1] = (__bf16)a.y; o[2] = (__bf16)a.z; o[3] = (__bf16)a.w;
    o[4] = (__bf16)b.x; o[5] = (__bf16)b.y; o[6] = (__bf16)b.z; o[7] = (__bf16)b.w;
}

// ---------------------------------------------------------------------------
// C = A[M_,K]bf16 * Bm[N,K]bf16^T + bias(f32); opt GELU / pe-add.
// PACK: 0 = row-major C; 1 = K-packed; 2 = V-packed; 3 = fused k|v (N=2048).
// BM=128, BN=64, BK=64; 4 waves, 16 MFMA/wave/step.
// 3-deep counted-vmcnt pipeline: buffers t%3; per step
//   vmcnt(12) -> barrier -> ds_read -> lgkmcnt(0) -> barrier -> stage t+3
//   -> 16 MFMA.  vmcnt never drained to 0 in steady state.
// Swizzle chunk' = ch ^ (row&7) on both sides. XCD-chunked block swizzle.
// ---------------------------------------------------------------------------
template <int ACT, int ADD_PE, int PACK>
__global__ __launch_bounds__(256) void gemm_bf16(
    const __bf16* __restrict__ A, const __bf16* __restrict__ Bm,
    const float* __restrict__ bias, __bf16* __restrict__ C, int K,
    const float* __restrict__ pe, const float* __restrict__ bias2) {
    __shared__ __bf16 As[3][128 * 64];  // 48 KB
    __shared__ __bf16 Bs[3][64 * 64];   // 24 KB
    const int tid = threadIdx.x;
    const int lane = tid & 63;
    const int wid = tid >> 6;
    const int wm = wid >> 1;
    const int wn = wid & 1;
    const int l15 = lane & 15, lhi = lane >> 4;

    // XCD-chunked bijective swizzle (nwg % 8 == 0 for all grids used)
    const int gx = gridDim.x;
    const int id = blockIdx.y * gx + blockIdx.x;
    const int nwg = gx * gridDim.y;
    const int swz = (id & 7) * (nwg >> 3) + (id >> 3);
    const int m0 = (swz / gx) * 128;
    const int n0 = (swz % gx) * 64;

    // staging: A = 1024 chunks of 16B (4/thread), B = 512 chunks (2/thread).
    // chunk c -> LDS slot c (linear); source chunk = (c&7) ^ (row&7).
    const __bf16* pa[4];
    int laoff[4];
#pragma unroll
    for (int j = 0; j < 4; ++j) {
        const int ca = wid * 256 + j * 64 + lane;
        const int row = ca >> 3, ch = ca & 7;
        pa[j] = A + (size_t)(m0 + row) * K + ((ch ^ (row & 7)) << 3);
        laoff[j] = ca * 8;
    }
    const __bf16* pb[2];
    int lboff[2];
#pragma unroll
    for (int j = 0; j < 2; ++j) {
        const int cb = wid * 128 + j * 64 + lane;
        const int row = cb >> 3, ch = cb & 7;
        pb[j] = Bm + (size_t)(n0 + row) * K + ((ch ^ (row & 7)) << 3);
        lboff[j] = cb * 8;
    }

    // ds_read offsets (elements): row*64 + ((kc*4+lhi)^(row&7))*8
    int aoff[4][2], boff[2][2];
#pragma unroll
    for (int mi = 0; mi < 4; ++mi) {
        const int row = wm * 64 + mi * 16 + l15;
#pragma unroll
        for (int kc = 0; kc < 2; ++kc)
            aoff[mi][kc] = row * 64 + (((kc * 4 + lhi) ^ (row & 7)) << 3);
    }
#pragma unroll
    for (int ni = 0; ni < 2; ++ni) {
        const int row = wn * 32 + ni * 16 + l15;
#pragma unroll
        for (int kc = 0; kc < 2; ++kc)
            boff[ni][kc] = row * 64 + (((kc * 4 + lhi) ^ (row & 7)) << 3);
    }

    f32x4 acc[4][2] = {};
    const int NT = K >> 6;

    auto STAGE = [&](int tt, int buf) {
        const size_t koff = (size_t)tt << 6;
#pragma unroll
        for (int j = 0; j < 4; ++j)
            __builtin_amdgcn_global_load_lds(
                (const __attribute__((address_space(1))) unsigned int*)(pa[j] + koff),
                (__attribute__((address_space(3))) unsigned int*)(
                    &As[buf][0] + laoff[j]), 16, 0, 0);
#pragma unroll
        for (int j = 0; j < 2; ++j)
            __builtin_amdgcn_global_load_lds(
                (const __attribute__((address_space(1))) unsigned int*)(pb[j] + koff),
                (__attribute__((address_space(3))) unsigned int*)(
                    &Bs[buf][0] + lboff[j]), 16, 0, 0);
    };

    // prologue: stage t=0,1,2 (18 loads in flight per thread)
    STAGE(0, 0);
    STAGE(1, 1);
    STAGE(2, 2);

    int cur = 0;
    for (int t = 0; t < NT; ++t) {
        // counted wait: ensure stage(t) complete. outstanding = 6*(min(t+3,NT)-t)
        if (t < NT - 2)
            asm volatile("s_waitcnt vmcnt(12)" ::: "memory");
        else if (t == NT - 2)
            asm volatile("s_waitcnt vmcnt(6)" ::: "memory");
        else
            asm volatile("s_waitcnt vmcnt(0)" ::: "memory");
        __builtin_amdgcn_s_barrier();  // all waves' stage(t) data in LDS

        const __bf16* Ab = &As[cur][0];
        const __bf16* Bb = &Bs[cur][0];
        bf16x8 af[4][2], bfr[2][2];
#pragma unroll
        for (int mi = 0; mi < 4; ++mi)
#pragma unroll
            for (int kc = 0; kc < 2; ++kc)
                af[mi][kc] = *(const bf16x8*)(Ab + aoff[mi][kc]);
#pragma unroll
        for (int ni = 0; ni < 2; ++ni)
#pragma unroll
            for (int kc = 0; kc < 2; ++kc)
                bfr[ni][kc] = *(const bf16x8*)(Bb + boff[ni][kc]);
        asm volatile("s_waitcnt lgkmcnt(0)" ::: "memory");  // reads retired
        __builtin_amdgcn_s_barrier();  // all waves done reading buf[cur]

        if (t + 3 < NT) STAGE(t + 3, cur);  // refill freed buffer

        __builtin_amdgcn_s_setprio(1);
#pragma unroll
        for (int mi = 0; mi < 4; ++mi)
#pragma unroll
            for (int ni = 0; ni < 2; ++ni)
#pragma unroll
                for (int kc = 0; kc < 2; ++kc)
                    acc[mi][ni] = __builtin_amdgcn_mfma_f32_16x16x32_bf16(
                        af[mi][kc], bfr[ni][kc], acc[mi][ni], 0, 0, 0);
        __builtin_amdgcn_s_setprio(0);
        cur = (cur == 2) ? 0 : cur + 1;
    }

    const int ccol0 = n0 + wn * 32 + l15;
    const int crow0 = m0 + wm * 64 + (lhi << 2);
#pragma unroll
    for (int mi = 0; mi < 4; ++mi) {
#pragma unroll
        for (int ni = 0; ni < 2; ++ni) {
            const int col = ccol0 + ni * 16;
            float bsum;
            if (PACK == 3) bsum = (col < 1024) ? bias[col] : bias2[col - 1024];
            else bsum = bias[col];
#pragma unroll
            for (int r = 0; r < 4; ++r) {
                const int row = crow0 + mi * 16 + r;
                float v = acc[mi][ni][r] + bsum;
                if (ADD_PE) v += pe[((row & (S_ - 1)) << 6) + (col & (D_ - 1))];
                if (ACT) v = gelu_exact(v);
                if (PACK == 0) {
                    C[(size_t)row * E_ + col] = (__bf16)v;
                } else if (PACK == 1) {
                    C[kpack_idx(row, col)] = (__bf16)v;
                } else if (PACK == 2) {
                    C[vpack_idx(row, col)] = (__bf16)v;
                } else {
                    if (col < 1024) {
                        v += pe[((row & (S_ - 1)) << 6) + (col & (D_ - 1))];
                        C[kpack_idx(row, col)] = (__bf16)v;
                    } else {
                        C[(size_t)M_ * E_ + vpack_idx(row, col - 1024)] = (__bf16)v;
                    }
                }
            }
        }
    }
}

// ---------------------------------------------------------------------------
// Swapped-QK MFMA flash attention, LDS-staged K/V shared by 8 waves.
// Block = 8 waves x 16 q-rows = 128 q-rows. KV tile = 64 keys.
// Double-buffered LDS prefetch. XCD-chunked swizzle groups same-bh blocks.
// ---------------------------------------------------------------------------
__global__ __launch_bounds__(512) void attn_mfma(
    const __bf16* __restrict__ Q, const __bf16* __restrict__ Kp,
    const __bf16* __restrict__ Vp, __bf16* __restrict__ O) {
    __shared__ __bf16 Slds[2][2][8 * 512];  // [buf][K/V][frag*512] = 32 KB
    const int tid = threadIdx.x;
    const int lane = tid & 63;
    const int w = tid >> 6;  // 0..7
    const int l15 = lane & 15, lhi = lane >> 4;

    // XCD-chunked swizzle over grid (8, 64): XCD c owns bh in {c*8..c*8+7}
    const int id = blockIdx.y * gridDim.x + blockIdx.x;  // 0..511
    const int swz = (id & 7) * 64 + (id >> 3);
    const int q0 = (swz & 7) * 128 + w * 16;
    const int bh = swz >> 3;
    const int bb = bh >> 4, hh = bh & 15;

    // Q fragments (B-operand), pre-scaled by 1/8 (exact)
    bf16x8 qf[2];
    {
        const __bf16* qrow =
            Q + (size_t)(bb * S_ + q0 + l15) * E_ + hh * 64 + lhi * 8;
#pragma unroll
        for (int kc = 0; kc < 2; ++kc) {
            const u16x8 raw = *(const u16x8*)(qrow + kc * 32);
            bf16x8 v;
#pragma unroll
            for (int j = 0; j < 8; ++j) v[j] = (__bf16)(bf2f(raw[j]) * 0.125f);
            qf[kc] = v;
        }
    }

    // wave w stages fragment w of K and of V for tile kt into buf
    const __bf16* kpw = Kp + ((size_t)bh * 16 * 8 + w) * 512 + lane * 8;
    const __bf16* vpw = Vp + ((size_t)bh * 16 * 8 + w) * 512 + lane * 8;

    float m_l = -1e30f, l_l = 0.f;
    f32x4 oacc[4] = {};

    // prologue: stage kt=0 into buf 0
    __builtin_amdgcn_global_load_lds(
        (const __attribute__((address_space(1))) unsigned int*)(kpw),
        (__attribute__((address_space(3))) unsigned int*)(&Slds[0][0][w * 512]),
        16, 0, 0);
    __builtin_amdgcn_global_load_lds(
        (const __attribute__((address_space(1))) unsigned int*)(vpw),
        (__attribute__((address_space(3))) unsigned int*)(&Slds[0][1][w * 512]),
        16, 0, 0);

#pragma unroll 2
    for (int kt = 0; kt < S_ / 64; ++kt) {
        const int cur = kt & 1;
        __syncthreads();  // drains vmcnt: buf[cur] staging complete, all waves
        if (kt < S_ / 64 - 1) {
            const size_t fo = (size_t)(kt + 1) * 8 * 512;
            __builtin_amdgcn_global_load_lds(
                (const __attribute__((address_space(1))) unsigned int*)(kpw + fo),
                (__attribute__((address_space(3))) unsigned int*)(
                    &Slds[cur ^ 1][0][w * 512]), 16, 0, 0);
            __builtin_amdgcn_global_load_lds(
                (const __attribute__((address_space(1))) unsigned int*)(vpw + fo),
                (__attribute__((address_space(3))) unsigned int*)(
                    &Slds[cur ^ 1][1][w * 512]), 16, 0, 0);
        }
        const __bf16* kl = &Slds[cur][0][0];
        const __bf16* vl = &Slds[cur][1][0];
        // S^T = mfma(K_frag, Q_frag): col = q = l15, row = kb*16 + lhi*4 + r
        f32x4 s[4];
#pragma unroll
        for (int kb = 0; kb < 4; ++kb) {
            const bf16x8 k0 = *(const bf16x8*)(kl + (kb * 2 + 0) * 512 + lane * 8);
            const bf16x8 k1 = *(const bf16x8*)(kl + (kb * 2 + 1) * 512 + lane * 8);
            f32x4 z = {};
            z = __builtin_amdgcn_mfma_f32_16x16x32_bf16(k0, qf[0], z, 0, 0, 0);
            s[kb] = __builtin_amdgcn_mfma_f32_16x16x32_bf16(k1, qf[1], z, 0, 0, 0);
        }
        // lane-local softmax over 16 in-lane scores + 2-shfl cross-group
        float mx0 = fmaxf(fmaxf(s[0][0], s[0][1]), fmaxf(s[0][2], s[0][3]));
        float mx1 = fmaxf(fmaxf(s[1][0], s[1][1]), fmaxf(s[1][2], s[1][3]));
        float mx2 = fmaxf(fmaxf(s[2][0], s[2][1]), fmaxf(s[2][2], s[2][3]));
        float mx3 = fmaxf(fmaxf(s[3][0], s[3][1]), fmaxf(s[3][2], s[3][3]));
        float mx = fmaxf(fmaxf(mx0, mx1), fmaxf(mx2, mx3));
        mx = fmaxf(mx, __shfl_xor(mx, 16));
        mx = fmaxf(mx, __shfl_xor(mx, 32));
        const float mnew = fmaxf(m_l, mx);
        const float corr = __expf(m_l - mnew);
        float p[4][4];
        float rs = 0.f;
#pragma unroll
        for (int kb = 0; kb < 4; ++kb) {
            float sb = 0.f;
#pragma unroll
            for (int r = 0; r < 4; ++r) {
                p[kb][r] = __expf(s[kb][r] - mnew);
                sb += p[kb][r];
            }
            rs += sb;
        }
        rs += __shfl_xor(rs, 16);
        rs += __shfl_xor(rs, 32);
        l_l = l_l * corr + rs;
        m_l = mnew;
#pragma unroll
        for (int db = 0; db < 4; ++db)
#pragma unroll
            for (int r = 0; r < 4; ++r) oacc[db][r] *= corr;
        // pack P^T into B-fragments (in-lane, key-permuted to match Vp)
        bf16x8 pf[2];
#pragma unroll
        for (int kc = 0; kc < 2; ++kc) {
            bf16x8 v;
#pragma unroll
            for (int r = 0; r < 4; ++r) {
                v[r] = (__bf16)p[kc * 2][r];
                v[r + 4] = (__bf16)p[kc * 2 + 1][r];
            }
            pf[kc] = v;
        }
#pragma unroll
        for (int db = 0; db < 4; ++db) {
            const bf16x8 v0 = *(const bf16x8*)(vl + (db * 2 + 0) * 512 + lane * 8);
            const bf16x8 v1 = *(const bf16x8*)(vl + (db * 2 + 1) * 512 + lane * 8);
            oacc[db] = __builtin_amdgcn_mfma_f32_16x16x32_bf16(v0, pf[0], oacc[db], 0, 0, 0);
            oacc[db] = __builtin_amdgcn_mfma_f32_16x16x32_bf16(v1, pf[1], oacc[db], 0, 0, 0);
        }
    }
    // epilogue: O[q][d], lane holds O^T[d = db*16 + lhi*4 + r][q = l15]
    const float inv_l = 1.f / l_l;
    __bf16* orow = O + (size_t)(bb * S_ + q0 + l15) * E_ + hh * 64 + lhi * 4;
#pragma unroll
    for (int db = 0; db < 4; ++db) {
        bf16x4 ov;
#pragma unroll
        for (int r = 0; r < 4; ++r) ov[r] = (__bf16)(oacc[db][r] * inv_l);
        *(bf16x4*)(orow + db * 16) = ov;
    }
}

// ---------------------------------------------------------------------------
// out[m] = bf16 x[m,:] . f32 W_out + b_out -> f32. One wave per row.
// ---------------------------------------------------------------------------
__global__ __launch_bounds__(256) void final_proj(
    const __bf16* __restrict__ X, const float* __restrict__ Wout,
    const float* __restrict__ bout, float* __restrict__ out) {
    const int wid = threadIdx.x >> 6, lane = threadIdx.x & 63;
    const int m = blockIdx.x * 4 + wid;
    const __bf16* xrow = X + (size_t)m * E_;
    float acc = 0.f;
#pragma unroll
    for (int c = 0; c < 2; ++c) {
        const int idx = c * 512 + lane * 8;
        const u16x8 xv = *(const u16x8*)(xrow + idx);
        const float4 w1 = *(const float4*)(Wout + idx);
        const float4 w2 = *(const float4*)(Wout + idx + 4);
        acc += bf2f(xv[0]) * w1.x + bf2f(xv[1]) * w1.y + bf2f(xv[2]) * w1.z +
               bf2f(xv[3]) * w1.w + bf2f(xv[4]) * w2.x + bf2f(xv[5]) * w2.y +
               bf2f(xv[6]) * w2.z + bf2f(xv[7]) * w2.w;
    }
#pragma unroll
    for (int off = 32; off; off >>= 1) acc += __shfl_xor(acc, off, 64);
    if (lane == 0) out[m] = acc + bout[0];
}

extern "C" void kernel_launch(void* const* d_in, const int* in_sizes, int n_in,
                              void* d_out, int out_size, void* d_ws, size_t ws_size,
                              hipStream_t stream) {
    const int* item_inputs = (const int*)d_in[0];
    const int* skill_inputs = (const int*)d_in[1];
    const float* emb_item = (const float*)d_in[5];
    const float* emb_skill = (const float*)d_in[6];
    const float* W_in = (const float*)d_in[7];
    const float* b_in = (const float*)d_in[8];
    const float* Wq = (const float*)d_in[9];
    const float* bq = (const float*)d_in[10];
    const float* Wk = (const float*)d_in[11];
    const float* bk = (const float*)d_in[12];
    const float* Wv = (const float*)d_in[13];
    const float* bv = (const float*)d_in[14];
    // d_in[15] Wg, d_in[16] bg: softmax-invariant, skipped.
    const float* pos_key = (const float*)d_in[17];
    const float* Wl = (const float*)d_in[18];
    const float* bl = (const float*)d_in[19];
    const float* W_out = (const float*)d_in[20];
    const float* b_out = (const float*)d_in[21];
    float* out = (float*)d_out;

    const size_t SZ = (size_t)M_ * E_;  // 4M
    __bf16* Xc = (__bf16*)d_ws;         // 8M elems (dead after embed GEMM)
    __bf16* X = Xc + (size_t)M_ * 2048;
    __bf16* Qb = X + SZ;
    __bf16* Kp = Qb + SZ;               // packed K fragments, 4M elems
    __bf16* Vp = Kp + SZ;               // packed V fragments, 4M (contiguous after Kp)
    __bf16* Winb = Vp + SZ;             // 2M elems
    __bf16* Wall = Winb + 2 * EE;       // 24M elems (all layers)

    const dim3 gg(E_ / 64, M_ / 128);   // (16, 32)
    const dim3 ggkv(2 * E_ / 64, M_ / 128);  // (32, 32) fused k|v
    const dim3 bb(256);

    embed_gather<<<dim3(M_), bb, 0, stream>>>(item_inputs, skill_inputs,
                                              emb_item, emb_skill, Xc);
    cvt_f32_bf16<<<dim3(2 * EE / 1024), bb, 0, stream>>>(W_in, Winb, 2 * EE);
    cvt_all_weights<<<dim3(L_ * 6 * EE / 1024), bb, 0, stream>>>(Wq, Wk, Wv, Wl, Wall);
    gemm_bf16<0, 0, 0><<<gg, bb, 0, stream>>>(Xc, Winb, b_in, X, 2048, nullptr, nullptr);

    for (int l = 0; l < L_; ++l) {
        __bf16* Wbuf = Wall + (size_t)l * 6 * EE;
        const float* pe_l = pos_key + (size_t)l * S_ * D_;
        gemm_bf16<0, 0, 0><<<gg, bb, 0, stream>>>(X, Wbuf + 0 * EE, bq + l * E_, Qb, E_, nullptr, nullptr);
        // fused k|v: B = [Wk; Wv] (contiguous in Wbuf), writes Kp then Vp
        gemm_bf16<0, 0, 3><<<ggkv, bb, 0, stream>>>(Qb, Wbuf + 1 * EE, bk + l * E_, Kp, E_, pe_l, bv + l * E_);
        attn_mfma<<<dim3(S_ / 128, B_ * H_), dim3(512), 0, stream>>>(Qb, Kp, Vp, X);
        gemm_bf16<1, 0, 0><<<gg, bb, 0, stream>>>(X, Wbuf + 3 * EE, bl + (l * 3 + 0) * E_, Qb, E_, nullptr, nullptr);
        gemm_bf16<1, 0, 0><<<gg, bb, 0, stream>>>(Qb, Wbuf + 4 * EE, bl + (l * 3 + 1) * E_, Kp, E_, nullptr, nullptr);
        gemm_bf16<1, 0, 0><<<gg, bb, 0, stream>>>(Kp, Wbuf + 5 * EE, bl + (l * 3 + 2) * E_, X, E_, nullptr, nullptr);
    }
    final_proj<<<dim3(M_ / 4), bb, 0, stream>>>(X, W_out, b_out, out);
}